// Round 2
// baseline (2507.247 us; speedup 1.0000x reference)
//
#include <hip/hip_runtime.h>

// Swin block. fp32 I/O (per reference dtypes), bf16 internal MFMA operands, fp32 trunk.
// Attention path in 2 batch-halves, MLP path in 4 batch-quarters -> ws peak ~90MB.

using bf16x8 = __attribute__((ext_vector_type(8))) short;
using f32x4  = __attribute__((ext_vector_type(4))) float;

#define CDIM  384
#define N3C   1152
#define NHID  1536

__device__ __forceinline__ float bf2f(unsigned short u){
  union { unsigned int i; float f; } x; x.i = ((unsigned int)u) << 16; return x.f;
}
__device__ __forceinline__ unsigned short f2bf(float f){
  union { float f; unsigned int i; } x; x.f = f;
  unsigned int r = x.i + 0x7fffu + ((x.i >> 16) & 1u);   // RNE
  return (unsigned short)(r >> 16);
}

__global__ __launch_bounds__(256)
void cvt_kern(const float* __restrict__ s, unsigned short* __restrict__ d, int n){
  int i = blockIdx.x * 256 + threadIdx.x;
  if (i < n) d[i] = f2bf(s[i]);
}

// ---------------- LayerNorm (+optional roll+window-partition gather), fp32 in, bf16 out ----------
__global__ __launch_bounds__(64)
void ln_kern(const float* __restrict__ xin, const float* __restrict__ g,
             const float* __restrict__ bsh, unsigned short* __restrict__ out,
             int row_off, int do_shift)
{
  int blk = blockIdx.x, t = threadIdx.x;
  size_t src;
  if (do_shift){
    int gl = row_off + blk;
    int bb = gl / 3136, rem = gl % 3136;
    int wi = rem / 49, l = rem % 49;
    int h = (wi >> 3) * 7 + l / 7;
    int w = (wi & 7) * 7 + l % 7;
    int sh = h + 3; if (sh >= 56) sh -= 56;    // roll(-3)
    int sw = w + 3; if (sw >= 56) sw -= 56;
    src = ((size_t)bb * 3136 + sh * 56 + sw) * CDIM;   // into full x
  } else {
    src = (size_t)blk * CDIM;                          // xin already offset
  }
  float v[6]; float s = 0.f;
  #pragma unroll
  for (int j = 0; j < 6; j++){ v[j] = xin[src + j*64 + t]; s += v[j]; }
  #pragma unroll
  for (int m = 32; m >= 1; m >>= 1) s += __shfl_xor(s, m);
  float mean = s * (1.f/384.f);
  float q = 0.f;
  #pragma unroll
  for (int j = 0; j < 6; j++){ float d = v[j] - mean; q += d * d; }
  #pragma unroll
  for (int m = 32; m >= 1; m >>= 1) q += __shfl_xor(q, m);
  float rstd = rsqrtf(q * (1.f/384.f) + 1e-5f);
  size_t dst = (size_t)blk * CDIM;
  #pragma unroll
  for (int j = 0; j < 6; j++){
    int c = j*64 + t;
    out[dst + c] = f2bf((v[j] - mean) * rstd * g[c] + bsh[c]);
  }
}

// ---------------- MFMA GEMM: C[M,N] = A[M,K]@B[K,N] (+epilogue) ----------------
// A: bf16 with stride lda. B: bf16 contiguous [K,N]. bias/resid fp32.
// MODE 0: bf16 out (qkv). 1: +bias, bf16 out (fc1).
// 2: proj: fp32 out = resid + val + bias, window-reverse permute.
// 3: fc2: fp32 RMW out += val + bias.
template<int MODE>
__global__ __launch_bounds__(256)
void gemm_kern(const unsigned short* __restrict__ A, int lda,
               const unsigned short* __restrict__ Bw, int K, int N,
               const float* __restrict__ bias, const float* __restrict__ resid,
               void* __restrict__ outv, int row_off)
{
  __shared__ __align__(16) unsigned short Al[64][40];   // [m][k], padded
  __shared__ __align__(16) unsigned short Bl[64][40];   // [n][k], padded (B transposed)
  int tid = threadIdx.x;
  int m0 = blockIdx.x * 64, n0 = blockIdx.y * 64;
  int lane = tid & 63, wv = tid >> 6;
  int wr = (wv >> 1) * 32, wc = (wv & 1) * 32;
  int ar = tid >> 2, acl = (tid & 3) * 8;   // A staging: row, col8
  int br = tid >> 3, bcl = (tid & 7) * 8;   // B staging: k-row, n-col8
  const int lr = lane & 15, lk = (lane >> 4) * 8;
  f32x4 acc[2][2] = {};
  for (int k0 = 0; k0 < K; k0 += 32){
    bf16x8 av = *(const bf16x8*)&A[(size_t)(m0 + ar) * lda + k0 + acl];
    bf16x8 bv = *(const bf16x8*)&Bw[(size_t)(k0 + br) * N + n0 + bcl];
    __syncthreads();
    *(bf16x8*)&Al[ar][acl] = av;
    #pragma unroll
    for (int i = 0; i < 8; i++) Bl[bcl + i][br] = (unsigned short)bv[i];
    __syncthreads();
    bf16x8 af0 = *(const bf16x8*)&Al[wr + lr][lk];
    bf16x8 af1 = *(const bf16x8*)&Al[wr + 16 + lr][lk];
    bf16x8 bf0 = *(const bf16x8*)&Bl[wc + lr][lk];
    bf16x8 bf1 = *(const bf16x8*)&Bl[wc + 16 + lr][lk];
    acc[0][0] = __builtin_amdgcn_mfma_f32_16x16x32_bf16(af0, bf0, acc[0][0], 0, 0, 0);
    acc[0][1] = __builtin_amdgcn_mfma_f32_16x16x32_bf16(af0, bf1, acc[0][1], 0, 0, 0);
    acc[1][0] = __builtin_amdgcn_mfma_f32_16x16x32_bf16(af1, bf0, acc[1][0], 0, 0, 0);
    acc[1][1] = __builtin_amdgcn_mfma_f32_16x16x32_bf16(af1, bf1, acc[1][1], 0, 0, 0);
  }
  #pragma unroll
  for (int mi = 0; mi < 2; mi++)
  #pragma unroll
  for (int ni = 0; ni < 2; ni++)
  #pragma unroll
  for (int j = 0; j < 4; j++){
    int row = m0 + wr + mi*16 + (lane >> 4) * 4 + j;   // C/D layout (m89/m91)
    int col = n0 + wc + ni*16 + lr;
    float val = acc[mi][ni][j];
    if (MODE == 0){
      ((unsigned short*)outv)[(size_t)row * N + col] = f2bf(val);
    } else if (MODE == 1){
      ((unsigned short*)outv)[(size_t)row * N + col] = f2bf(val + bias[col]);
    } else if (MODE == 2){
      val += bias[col];
      int gl = row_off + row;
      int bb = gl / 3136, rem = gl % 3136;
      int wi = rem / 49, l = rem % 49;
      int n = ((wi >> 3) * 7 + l / 7) * 56 + (wi & 7) * 7 + l % 7;  // window reverse (no un-roll)
      size_t idx = ((size_t)bb * 3136 + n) * CDIM + col;
      ((float*)outv)[idx] = resid[idx] + val;
    } else {
      size_t idx = (size_t)(row_off + row) * CDIM + col;
      ((float*)outv)[idx] = resid[idx] + val + bias[col];
    }
  }
}

// ---------------- Windowed attention: one wave per (window, head); writes into q-slot ----------
__global__ __launch_bounds__(64)
void attn_kern(unsigned short* __restrict__ qkv)
{
  __shared__ __align__(16) float ql[49][33], kl[49][33], vl[49][33];
  int blk = blockIdx.x;
  int win = blk / 12, head = blk % 12;
  int t = threadIdx.x;
  size_t base = (size_t)win * 49 * N3C + head * 32;
  for (int i = t; i < 49 * 32; i += 64){
    int r = i >> 5, c = i & 31;
    size_t rb = base + (size_t)r * N3C + c;
    ql[r][c] = bf2f(qkv[rb]);
    kl[r][c] = bf2f(qkv[rb + 384]);
    vl[r][c] = bf2f(qkv[rb + 768]);
  }
  __syncthreads();
  if (t >= 49) return;
  float qr[32];
  #pragma unroll
  for (int d = 0; d < 32; d++) qr[d] = ql[t][d];
  int wi = win & 63;   // window-in-image (halves are multiples of 64 windows)
  int hq = (wi >> 3) * 7 + t / 7, wq = (wi & 7) * 7 + t % 7;
  int idq = (hq < 49 ? 0 : (hq < 53 ? 1 : 2)) * 3 + (wq < 49 ? 0 : (wq < 53 ? 1 : 2));
  const float scale = 0.17677669529663687f;
  float S[49]; float mx = -1e30f;
  #pragma unroll
  for (int j = 0; j < 49; j++){
    float s0 = 0.f, s1 = 0.f, s2 = 0.f, s3 = 0.f;
    #pragma unroll
    for (int d = 0; d < 32; d += 4){
      s0 += qr[d    ] * kl[j][d    ];
      s1 += qr[d + 1] * kl[j][d + 1];
      s2 += qr[d + 2] * kl[j][d + 2];
      s3 += qr[d + 3] * kl[j][d + 3];
    }
    int hk = (wi >> 3) * 7 + j / 7, wk = (wi & 7) * 7 + j % 7;
    int idk = (hk < 49 ? 0 : (hk < 53 ? 1 : 2)) * 3 + (wk < 49 ? 0 : (wk < 53 ? 1 : 2));
    float s = (s0 + s1 + s2 + s3) * scale + ((idq != idk) ? -100.f : 0.f);
    S[j] = s; mx = fmaxf(mx, s);
  }
  float sum = 0.f;
  #pragma unroll
  for (int j = 0; j < 49; j++){ float e = expf(S[j] - mx); S[j] = e; sum += e; }
  float inv = 1.f / sum;
  float o[32];
  #pragma unroll
  for (int d = 0; d < 32; d++) o[d] = 0.f;
  #pragma unroll
  for (int j = 0; j < 49; j++){
    float p = S[j];
    #pragma unroll
    for (int d = 0; d < 32; d++) o[d] += p * vl[j][d];
  }
  // write into own q-slot (no other block reads it)
  size_t ob = ((size_t)win * 49 + t) * N3C + head * 32;
  #pragma unroll
  for (int g2 = 0; g2 < 4; g2++){
    bf16x8 ovv;
    #pragma unroll
    for (int d = 0; d < 8; d++) ovv[d] = (short)f2bf(o[g2*8 + d] * inv);
    *(bf16x8*)&qkv[ob + g2*8] = ovv;
  }
}

// ---------------- Depthwise 3x3 conv + bias + exact GELU (bf16 in/out, fp32 weights) ----------
__global__ __launch_bounds__(192)
void conv_gelu_kern(const unsigned short* __restrict__ x1, const float* __restrict__ kw,
                    const float* __restrict__ kb, unsigned short* __restrict__ out)
{
  int n = blockIdx.x;                    // local token within quarter (4 whole images)
  int rem = n % 3136;
  int h = rem / 56, w = rem % 56;
  int c0 = threadIdx.x * 8;
  float acc[8] = {0.f,0.f,0.f,0.f,0.f,0.f,0.f,0.f};
  #pragma unroll
  for (int dh = -1; dh <= 1; dh++){
    int hh = h + dh; if (hh < 0 || hh >= 56) continue;
    #pragma unroll
    for (int dw = -1; dw <= 1; dw++){
      int ww = w + dw; if (ww < 0 || ww >= 56) continue;
      const unsigned short* rp = &x1[((size_t)n + dh*56 + dw) * NHID + c0];
      bf16x8 rv = *(const bf16x8*)rp;
      #pragma unroll
      for (int i = 0; i < 8; i++)
        acc[i] += bf2f((unsigned short)rv[i]) * kw[(c0 + i) * 9 + (dh + 1) * 3 + (dw + 1)];
    }
  }
  size_t ob = (size_t)n * NHID + c0;
  #pragma unroll
  for (int i = 0; i < 8; i++){
    float v = acc[i] + kb[c0 + i];
    out[ob + i] = f2bf(0.5f * v * (1.f + erff(v * 0.70710678118654752f)));
  }
}

extern "C" void kernel_launch(void* const* d_in, const int* in_sizes, int n_in,
                              void* d_out, int out_size, void* d_ws, size_t ws_size,
                              hipStream_t stream)
{
  const float* x      = (const float*)d_in[0];
  const float* ln1_g  = (const float*)d_in[1];
  const float* ln1_b  = (const float*)d_in[2];
  const float* qkv_w  = (const float*)d_in[3];
  const float* proj_w = (const float*)d_in[4];
  const float* proj_b = (const float*)d_in[5];
  const float* ln2_g  = (const float*)d_in[6];
  const float* ln2_b  = (const float*)d_in[7];
  const float* fc1_w  = (const float*)d_in[8];
  const float* fc1_b  = (const float*)d_in[9];
  const float* dw_k   = (const float*)d_in[10];
  const float* dw_b   = (const float*)d_in[11];
  const float* fc2_w  = (const float*)d_in[12];
  const float* fc2_b  = (const float*)d_in[13];
  float* outp = (float*)d_out;

  // workspace layout (bytes); attn era and MLP era reuse [0, 86704128)
  const size_t WS_NEED = 90243072;
  if (ws_size < WS_NEED) return;   // loud failure (wrong answer), not a crash
  char* ws = (char*)d_ws;
  unsigned short* xw   = (unsigned short*)(ws);               // 25088*384*2  = 19,267,584
  unsigned short* qkvh = (unsigned short*)(ws + 19267584);    // 25088*1152*2 = 57,802,752
  unsigned short* xn2q = (unsigned short*)(ws);               // 12544*384*2  =  9,633,792
  unsigned short* x1q  = (unsigned short*)(ws + 9633792);     // 12544*1536*2 = 38,535,168
  unsigned short* x1gq = (unsigned short*)(ws + 48168960);    // 12544*1536*2 = 38,535,168
  unsigned short* wqkv = (unsigned short*)(ws + 86704128);    // 442368*2
  unsigned short* wproj= (unsigned short*)(ws + 87588864);    // 147456*2
  unsigned short* wfc1 = (unsigned short*)(ws + 87883776);    // 589824*2
  unsigned short* wfc2 = (unsigned short*)(ws + 89063424);    // 589824*2

  // 0) weights fp32 -> bf16
  cvt_kern<<<(442368+255)/256, 256, 0, stream>>>(qkv_w,  wqkv, 442368);
  cvt_kern<<<(147456+255)/256, 256, 0, stream>>>(proj_w, wproj, 147456);
  cvt_kern<<<(589824+255)/256, 256, 0, stream>>>(fc1_w,  wfc1, 589824);
  cvt_kern<<<(589824+255)/256, 256, 0, stream>>>(fc2_w,  wfc2, 589824);

  // ---- attention path, two batch halves (25088 tokens = 512 windows each) ----
  for (int hf = 0; hf < 2; hf++){
    int ro = hf * 25088;
    // LN1 + roll + window partition (gathers from full x)
    ln_kern<<<25088, 64, 0, stream>>>(x, ln1_g, ln1_b, xw, ro, 1);
    // qkv = xw @ qkv_w
    gemm_kern<0><<<dim3(392, 18), 256, 0, stream>>>(xw, 384, wqkv, 384, 1152,
                                                    nullptr, nullptr, qkvh, 0);
    // windowed attention, in-place into q-slot
    attn_kern<<<6144, 64, 0, stream>>>(qkvh);
    // proj + bias + window-reverse + residual(x) -> d_out (fp32 trunk)
    gemm_kern<2><<<dim3(392, 6), 256, 0, stream>>>(qkvh, 1152, wproj, 384, 384,
                                                   proj_b, x, outp, ro);
  }

  // ---- MLP path, four batch quarters (12544 tokens = 4 whole images each) ----
  for (int qt = 0; qt < 4; qt++){
    int ro = qt * 12544;
    ln_kern<<<12544, 64, 0, stream>>>(outp + (size_t)ro * CDIM, ln2_g, ln2_b, xn2q, 0, 0);
    gemm_kern<1><<<dim3(196, 24), 256, 0, stream>>>(xn2q, 384, wfc1, 384, 1536,
                                                    fc1_b, nullptr, x1q, 0);
    conv_gelu_kern<<<12544, 192, 0, stream>>>(x1q, dw_k, dw_b, x1gq);
    gemm_kern<3><<<dim3(196, 6), 256, 0, stream>>>(x1gq, 1536, wfc2, 1536, 384,
                                                   fc2_b, outp, outp, ro);
  }
}

// Round 3
// 1628.831 us; speedup vs baseline: 1.5393x; 1.5393x over previous
//
#include <hip/hip_runtime.h>

// Swin block. fp32 I/O, bf16 internal MFMA operands, fp32 trunk.
// R2: conv_gelu rewritten — LDS-staged transposed weights + 8 tokens/block.

using bf16x8 = __attribute__((ext_vector_type(8))) short;
using f32x4  = __attribute__((ext_vector_type(4))) float;

#define CDIM  384
#define N3C   1152
#define NHID  1536

__device__ __forceinline__ float bf2f(unsigned short u){
  union { unsigned int i; float f; } x; x.i = ((unsigned int)u) << 16; return x.f;
}
__device__ __forceinline__ unsigned short f2bf(float f){
  union { float f; unsigned int i; } x; x.f = f;
  unsigned int r = x.i + 0x7fffu + ((x.i >> 16) & 1u);   // RNE
  return (unsigned short)(r >> 16);
}

__global__ __launch_bounds__(256)
void cvt_kern(const float* __restrict__ s, unsigned short* __restrict__ d, int n){
  int i = blockIdx.x * 256 + threadIdx.x;
  if (i < n) d[i] = f2bf(s[i]);
}

// ---------------- LayerNorm (+optional roll+window-partition gather), fp32 in, bf16 out ----------
__global__ __launch_bounds__(64)
void ln_kern(const float* __restrict__ xin, const float* __restrict__ g,
             const float* __restrict__ bsh, unsigned short* __restrict__ out,
             int row_off, int do_shift)
{
  int blk = blockIdx.x, t = threadIdx.x;
  size_t src;
  if (do_shift){
    int gl = row_off + blk;
    int bb = gl / 3136, rem = gl % 3136;
    int wi = rem / 49, l = rem % 49;
    int h = (wi >> 3) * 7 + l / 7;
    int w = (wi & 7) * 7 + l % 7;
    int sh = h + 3; if (sh >= 56) sh -= 56;    // roll(-3)
    int sw = w + 3; if (sw >= 56) sw -= 56;
    src = ((size_t)bb * 3136 + sh * 56 + sw) * CDIM;   // into full x
  } else {
    src = (size_t)blk * CDIM;                          // xin already offset
  }
  float v[6]; float s = 0.f;
  #pragma unroll
  for (int j = 0; j < 6; j++){ v[j] = xin[src + j*64 + t]; s += v[j]; }
  #pragma unroll
  for (int m = 32; m >= 1; m >>= 1) s += __shfl_xor(s, m);
  float mean = s * (1.f/384.f);
  float q = 0.f;
  #pragma unroll
  for (int j = 0; j < 6; j++){ float d = v[j] - mean; q += d * d; }
  #pragma unroll
  for (int m = 32; m >= 1; m >>= 1) q += __shfl_xor(q, m);
  float rstd = rsqrtf(q * (1.f/384.f) + 1e-5f);
  size_t dst = (size_t)blk * CDIM;
  #pragma unroll
  for (int j = 0; j < 6; j++){
    int c = j*64 + t;
    out[dst + c] = f2bf((v[j] - mean) * rstd * g[c] + bsh[c]);
  }
}

// ---------------- MFMA GEMM: C[M,N] = A[M,K]@B[K,N] (+epilogue) ----------------
template<int MODE>
__global__ __launch_bounds__(256)
void gemm_kern(const unsigned short* __restrict__ A, int lda,
               const unsigned short* __restrict__ Bw, int K, int N,
               const float* __restrict__ bias, const float* __restrict__ resid,
               void* __restrict__ outv, int row_off)
{
  __shared__ __align__(16) unsigned short Al[64][40];   // [m][k], padded
  __shared__ __align__(16) unsigned short Bl[64][40];   // [n][k], padded (B transposed)
  int tid = threadIdx.x;
  int m0 = blockIdx.x * 64, n0 = blockIdx.y * 64;
  int lane = tid & 63, wv = tid >> 6;
  int wr = (wv >> 1) * 32, wc = (wv & 1) * 32;
  int ar = tid >> 2, acl = (tid & 3) * 8;   // A staging: row, col8
  int br = tid >> 3, bcl = (tid & 7) * 8;   // B staging: k-row, n-col8
  const int lr = lane & 15, lk = (lane >> 4) * 8;
  f32x4 acc[2][2] = {};
  for (int k0 = 0; k0 < K; k0 += 32){
    bf16x8 av = *(const bf16x8*)&A[(size_t)(m0 + ar) * lda + k0 + acl];
    bf16x8 bv = *(const bf16x8*)&Bw[(size_t)(k0 + br) * N + n0 + bcl];
    __syncthreads();
    *(bf16x8*)&Al[ar][acl] = av;
    #pragma unroll
    for (int i = 0; i < 8; i++) Bl[bcl + i][br] = (unsigned short)bv[i];
    __syncthreads();
    bf16x8 af0 = *(const bf16x8*)&Al[wr + lr][lk];
    bf16x8 af1 = *(const bf16x8*)&Al[wr + 16 + lr][lk];
    bf16x8 bf0 = *(const bf16x8*)&Bl[wc + lr][lk];
    bf16x8 bf1 = *(const bf16x8*)&Bl[wc + 16 + lr][lk];
    acc[0][0] = __builtin_amdgcn_mfma_f32_16x16x32_bf16(af0, bf0, acc[0][0], 0, 0, 0);
    acc[0][1] = __builtin_amdgcn_mfma_f32_16x16x32_bf16(af0, bf1, acc[0][1], 0, 0, 0);
    acc[1][0] = __builtin_amdgcn_mfma_f32_16x16x32_bf16(af1, bf0, acc[1][0], 0, 0, 0);
    acc[1][1] = __builtin_amdgcn_mfma_f32_16x16x32_bf16(af1, bf1, acc[1][1], 0, 0, 0);
  }
  #pragma unroll
  for (int mi = 0; mi < 2; mi++)
  #pragma unroll
  for (int ni = 0; ni < 2; ni++)
  #pragma unroll
  for (int j = 0; j < 4; j++){
    int row = m0 + wr + mi*16 + (lane >> 4) * 4 + j;   // C/D layout (m89/m91)
    int col = n0 + wc + ni*16 + lr;
    float val = acc[mi][ni][j];
    if (MODE == 0){
      ((unsigned short*)outv)[(size_t)row * N + col] = f2bf(val);
    } else if (MODE == 1){
      ((unsigned short*)outv)[(size_t)row * N + col] = f2bf(val + bias[col]);
    } else if (MODE == 2){
      val += bias[col];
      int gl = row_off + row;
      int bb = gl / 3136, rem = gl % 3136;
      int wi = rem / 49, l = rem % 49;
      int n = ((wi >> 3) * 7 + l / 7) * 56 + (wi & 7) * 7 + l % 7;  // window reverse (no un-roll)
      size_t idx = ((size_t)bb * 3136 + n) * CDIM + col;
      ((float*)outv)[idx] = resid[idx] + val;
    } else {
      size_t idx = (size_t)(row_off + row) * CDIM + col;
      ((float*)outv)[idx] = resid[idx] + val + bias[col];
    }
  }
}

// ---------------- Windowed attention: one wave per (window, head); writes into q-slot ----------
__global__ __launch_bounds__(64)
void attn_kern(unsigned short* __restrict__ qkv)
{
  __shared__ __align__(16) float ql[49][33], kl[49][33], vl[49][33];
  int blk = blockIdx.x;
  int win = blk / 12, head = blk % 12;
  int t = threadIdx.x;
  size_t base = (size_t)win * 49 * N3C + head * 32;
  for (int i = t; i < 49 * 32; i += 64){
    int r = i >> 5, c = i & 31;
    size_t rb = base + (size_t)r * N3C + c;
    ql[r][c] = bf2f(qkv[rb]);
    kl[r][c] = bf2f(qkv[rb + 384]);
    vl[r][c] = bf2f(qkv[rb + 768]);
  }
  __syncthreads();
  if (t >= 49) return;
  float qr[32];
  #pragma unroll
  for (int d = 0; d < 32; d++) qr[d] = ql[t][d];
  int wi = win & 63;
  int hq = (wi >> 3) * 7 + t / 7, wq = (wi & 7) * 7 + t % 7;
  int idq = (hq < 49 ? 0 : (hq < 53 ? 1 : 2)) * 3 + (wq < 49 ? 0 : (wq < 53 ? 1 : 2));
  const float scale = 0.17677669529663687f;
  float S[49]; float mx = -1e30f;
  #pragma unroll
  for (int j = 0; j < 49; j++){
    float s0 = 0.f, s1 = 0.f, s2 = 0.f, s3 = 0.f;
    #pragma unroll
    for (int d = 0; d < 32; d += 4){
      s0 += qr[d    ] * kl[j][d    ];
      s1 += qr[d + 1] * kl[j][d + 1];
      s2 += qr[d + 2] * kl[j][d + 2];
      s3 += qr[d + 3] * kl[j][d + 3];
    }
    int hk = (wi >> 3) * 7 + j / 7, wk = (wi & 7) * 7 + j % 7;
    int idk = (hk < 49 ? 0 : (hk < 53 ? 1 : 2)) * 3 + (wk < 49 ? 0 : (wk < 53 ? 1 : 2));
    float s = (s0 + s1 + s2 + s3) * scale + ((idq != idk) ? -100.f : 0.f);
    S[j] = s; mx = fmaxf(mx, s);
  }
  float sum = 0.f;
  #pragma unroll
  for (int j = 0; j < 49; j++){ float e = expf(S[j] - mx); S[j] = e; sum += e; }
  float inv = 1.f / sum;
  float o[32];
  #pragma unroll
  for (int d = 0; d < 32; d++) o[d] = 0.f;
  #pragma unroll
  for (int j = 0; j < 49; j++){
    float p = S[j];
    #pragma unroll
    for (int d = 0; d < 32; d++) o[d] += p * vl[j][d];
  }
  size_t ob = ((size_t)win * 49 + t) * N3C + head * 32;
  #pragma unroll
  for (int g2 = 0; g2 < 4; g2++){
    bf16x8 ovv;
    #pragma unroll
    for (int d = 0; d < 8; d++) ovv[d] = (short)f2bf(o[g2*8 + d] * inv);
    *(bf16x8*)&qkv[ob + g2*8] = ovv;
  }
}

// ---------------- Depthwise 3x3 conv + bias + exact GELU ----------------
// R2: weights staged once per block into LDS as [tap][channel] bf16; 8 tokens/block.
#define CONV_T 8
__global__ __launch_bounds__(192)
void conv_gelu_kern(const unsigned short* __restrict__ x1, const float* __restrict__ kw,
                    const float* __restrict__ kb, unsigned short* __restrict__ out)
{
  __shared__ __align__(16) unsigned short wl[9][NHID];   // 27,648 B
  int tid = threadIdx.x;
  for (int i = tid; i < NHID * 9; i += 192){
    int c = i / 9, tap = i % 9;                 // coalesced global read, scattered LDS write
    wl[tap][c] = f2bf(kw[i]);
  }
  __syncthreads();
  int c0 = tid * 8;
  bf16x8 wv[9];
  #pragma unroll
  for (int j = 0; j < 9; j++) wv[j] = *(const bf16x8*)&wl[j][c0];
  float bias[8];
  #pragma unroll
  for (int i = 0; i < 8; i++) bias[i] = kb[c0 + i];

  int n0 = blockIdx.x * CONV_T;
  for (int t = 0; t < CONV_T; t++){
    int n = n0 + t;                             // wave-uniform
    int rem = n % 3136;
    int h = rem / 56, w = rem % 56;
    float acc[8] = {0.f,0.f,0.f,0.f,0.f,0.f,0.f,0.f};
    #pragma unroll
    for (int dh = -1; dh <= 1; dh++){
      int hh = h + dh; if (hh < 0 || hh >= 56) continue;
      #pragma unroll
      for (int dw = -1; dw <= 1; dw++){
        int ww = w + dw; if (ww < 0 || ww >= 56) continue;
        bf16x8 rv = *(const bf16x8*)&x1[((size_t)n + dh*56 + dw) * NHID + c0];
        int j = (dh + 1) * 3 + (dw + 1);
        #pragma unroll
        for (int i = 0; i < 8; i++)
          acc[i] += bf2f((unsigned short)rv[i]) * bf2f((unsigned short)wv[j][i]);
      }
    }
    size_t ob = (size_t)n * NHID + c0;
    bf16x8 ov;
    #pragma unroll
    for (int i = 0; i < 8; i++){
      float v = acc[i] + bias[i];
      ov[i] = (short)f2bf(0.5f * v * (1.f + erff(v * 0.70710678118654752f)));
    }
    *(bf16x8*)&out[ob] = ov;
  }
}

extern "C" void kernel_launch(void* const* d_in, const int* in_sizes, int n_in,
                              void* d_out, int out_size, void* d_ws, size_t ws_size,
                              hipStream_t stream)
{
  const float* x      = (const float*)d_in[0];
  const float* ln1_g  = (const float*)d_in[1];
  const float* ln1_b  = (const float*)d_in[2];
  const float* qkv_w  = (const float*)d_in[3];
  const float* proj_w = (const float*)d_in[4];
  const float* proj_b = (const float*)d_in[5];
  const float* ln2_g  = (const float*)d_in[6];
  const float* ln2_b  = (const float*)d_in[7];
  const float* fc1_w  = (const float*)d_in[8];
  const float* fc1_b  = (const float*)d_in[9];
  const float* dw_k   = (const float*)d_in[10];
  const float* dw_b   = (const float*)d_in[11];
  const float* fc2_w  = (const float*)d_in[12];
  const float* fc2_b  = (const float*)d_in[13];
  float* outp = (float*)d_out;

  const size_t WS_NEED = 90243072;
  if (ws_size < WS_NEED) return;   // loud failure (wrong answer), not a crash
  char* ws = (char*)d_ws;
  unsigned short* xw   = (unsigned short*)(ws);               // 25088*384*2  = 19,267,584
  unsigned short* qkvh = (unsigned short*)(ws + 19267584);    // 25088*1152*2 = 57,802,752
  unsigned short* xn2q = (unsigned short*)(ws);               // 12544*384*2  =  9,633,792
  unsigned short* x1q  = (unsigned short*)(ws + 9633792);     // 12544*1536*2 = 38,535,168
  unsigned short* x1gq = (unsigned short*)(ws + 48168960);    // 12544*1536*2 = 38,535,168
  unsigned short* wqkv = (unsigned short*)(ws + 86704128);    // 442368*2
  unsigned short* wproj= (unsigned short*)(ws + 87588864);    // 147456*2
  unsigned short* wfc1 = (unsigned short*)(ws + 87883776);    // 589824*2
  unsigned short* wfc2 = (unsigned short*)(ws + 89063424);    // 589824*2

  // 0) weights fp32 -> bf16
  cvt_kern<<<(442368+255)/256, 256, 0, stream>>>(qkv_w,  wqkv, 442368);
  cvt_kern<<<(147456+255)/256, 256, 0, stream>>>(proj_w, wproj, 147456);
  cvt_kern<<<(589824+255)/256, 256, 0, stream>>>(fc1_w,  wfc1, 589824);
  cvt_kern<<<(589824+255)/256, 256, 0, stream>>>(fc2_w,  wfc2, 589824);

  // ---- attention path, two batch halves (25088 tokens = 512 windows each) ----
  for (int hf = 0; hf < 2; hf++){
    int ro = hf * 25088;
    ln_kern<<<25088, 64, 0, stream>>>(x, ln1_g, ln1_b, xw, ro, 1);
    gemm_kern<0><<<dim3(392, 18), 256, 0, stream>>>(xw, 384, wqkv, 384, 1152,
                                                    nullptr, nullptr, qkvh, 0);
    attn_kern<<<6144, 64, 0, stream>>>(qkvh);
    gemm_kern<2><<<dim3(392, 6), 256, 0, stream>>>(qkvh, 1152, wproj, 384, 384,
                                                   proj_b, x, outp, ro);
  }

  // ---- MLP path, four batch quarters (12544 tokens = 4 whole images each) ----
  for (int qt = 0; qt < 4; qt++){
    int ro = qt * 12544;
    ln_kern<<<12544, 64, 0, stream>>>(outp + (size_t)ro * CDIM, ln2_g, ln2_b, xn2q, 0, 0);
    gemm_kern<1><<<dim3(196, 24), 256, 0, stream>>>(xn2q, 384, wfc1, 384, 1536,
                                                    fc1_b, nullptr, x1q, 0);
    conv_gelu_kern<<<12544 / CONV_T, 192, 0, stream>>>(x1q, dw_k, dw_b, x1gq);
    gemm_kern<3><<<dim3(196, 6), 256, 0, stream>>>(x1gq, 1536, wfc2, 1536, 384,
                                                   fc2_b, outp, outp, ro);
  }
}

// Round 4
// 1136.570 us; speedup vs baseline: 2.2060x; 1.4331x over previous
//
#include <hip/hip_runtime.h>

// Swin block. fp32 I/O, bf16 internal MFMA operands, fp32 trunk.
// R3: m97-style GEMM (128-tile, global_load_lds w16, pre-transposed weights);
//     attn drops Q from LDS (12 blocks/CU).

using bf16x8 = __attribute__((ext_vector_type(8))) short;
using f32x4  = __attribute__((ext_vector_type(4))) float;

#define CDIM  384
#define N3C   1152
#define NHID  1536

__device__ __forceinline__ float bf2f(unsigned short u){
  union { unsigned int i; float f; } x; x.i = ((unsigned int)u) << 16; return x.f;
}
__device__ __forceinline__ unsigned short f2bf(float f){
  union { float f; unsigned int i; } x; x.f = f;
  unsigned int r = x.i + 0x7fffu + ((x.i >> 16) & 1u);   // RNE
  return (unsigned short)(r >> 16);
}
__device__ __forceinline__ void gload16(const void* g, void* l){
  __builtin_amdgcn_global_load_lds(
      (const __attribute__((address_space(1))) unsigned int*)g,
      (__attribute__((address_space(3))) unsigned int*)l, 16, 0, 0);
}

// ---------------- transpose-convert: wt[n*K+k] = bf16(w[k*N+n]) ----------------
__global__ __launch_bounds__(256)
void cvtT_kern(const float* __restrict__ w, unsigned short* __restrict__ wt, int K, int N){
  __shared__ unsigned short t[32][33];
  int bk = blockIdx.x, bn = blockIdx.y;
  int tr = threadIdx.x >> 5, tc = threadIdx.x & 31;
  #pragma unroll
  for (int r = tr; r < 32; r += 8)
    t[r][tc] = f2bf(w[(size_t)(bk*32 + r) * N + bn*32 + tc]);
  __syncthreads();
  #pragma unroll
  for (int r = tr; r < 32; r += 8)
    wt[(size_t)(bn*32 + r) * K + bk*32 + tc] = t[tc][r];
}

// ---------------- LayerNorm (+optional roll+window-partition gather), fp32 in, bf16 out ----------
__global__ __launch_bounds__(64)
void ln_kern(const float* __restrict__ xin, const float* __restrict__ g,
             const float* __restrict__ bsh, unsigned short* __restrict__ out,
             int row_off, int do_shift)
{
  int blk = blockIdx.x, t = threadIdx.x;
  size_t src;
  if (do_shift){
    int gl = row_off + blk;
    int bb = gl / 3136, rem = gl % 3136;
    int wi = rem / 49, l = rem % 49;
    int h = (wi >> 3) * 7 + l / 7;
    int w = (wi & 7) * 7 + l % 7;
    int sh = h + 3; if (sh >= 56) sh -= 56;    // roll(-3)
    int sw = w + 3; if (sw >= 56) sw -= 56;
    src = ((size_t)bb * 3136 + sh * 56 + sw) * CDIM;
  } else {
    src = (size_t)blk * CDIM;
  }
  float v[6]; float s = 0.f;
  #pragma unroll
  for (int j = 0; j < 6; j++){ v[j] = xin[src + j*64 + t]; s += v[j]; }
  #pragma unroll
  for (int m = 32; m >= 1; m >>= 1) s += __shfl_xor(s, m);
  float mean = s * (1.f/384.f);
  float q = 0.f;
  #pragma unroll
  for (int j = 0; j < 6; j++){ float d = v[j] - mean; q += d * d; }
  #pragma unroll
  for (int m = 32; m >= 1; m >>= 1) q += __shfl_xor(q, m);
  float rstd = rsqrtf(q * (1.f/384.f) + 1e-5f);
  size_t dst = (size_t)blk * CDIM;
  #pragma unroll
  for (int j = 0; j < 6; j++){
    int c = j*64 + t;
    out[dst + c] = f2bf((v[j] - mean) * rstd * g[c] + bsh[c]);
  }
}

// ---------------- MFMA GEMM, m97-style: C[M,N] = A[M,K] @ Bt[N,K]^T ----------------
// 128xBN tile, 4 waves (2x2), global_load_lds staging, 2-barrier K-loop.
// MODE 0: bf16 out. 1: +bias, bf16 out. 2: proj epilogue. 3: fc2 epilogue.
template<int MODE, int BN>
__global__ __launch_bounds__(256)
void gemm_kern(const unsigned short* __restrict__ A, int lda,
               const unsigned short* __restrict__ Bt, int K, int N,
               const float* __restrict__ bias, const float* __restrict__ resid,
               void* __restrict__ outv, int row_off)
{
  constexpr int NI = BN / 32;
  __shared__ __align__(16) unsigned short Al[128 * 32];
  __shared__ __align__(16) unsigned short Bl[BN * 32];
  int tid = threadIdx.x;
  int lane = tid & 63, wv = tid >> 6;
  int m0 = blockIdx.x * 128, n0 = blockIdx.y * BN;
  const int wrow = (wv >> 1) * 64;
  const int wcol = (wv & 1) * (BN / 2);
  const int lr = lane & 15, lk = (lane >> 4) * 8;
  f32x4 acc[4][NI] = {};
  for (int k0 = 0; k0 < K; k0 += 32){
    __syncthreads();
    #pragma unroll
    for (int i = 0; i < 2; i++){
      int c = i*256 + tid;
      gload16(&A[(size_t)(m0 + (c >> 2)) * lda + k0 + (c & 3) * 8],
              &Al[(i*256 + wv*64) * 8]);
    }
    #pragma unroll
    for (int i = 0; i < BN/64; i++){
      int c = i*256 + tid;
      gload16(&Bt[(size_t)(n0 + (c >> 2)) * K + k0 + (c & 3) * 8],
              &Bl[(i*256 + wv*64) * 8]);
    }
    __syncthreads();
    bf16x8 af[4], bfr[NI];
    #pragma unroll
    for (int mi = 0; mi < 4; mi++) af[mi] = *(const bf16x8*)&Al[(wrow + mi*16 + lr)*32 + lk];
    #pragma unroll
    for (int ni = 0; ni < NI; ni++) bfr[ni] = *(const bf16x8*)&Bl[(wcol + ni*16 + lr)*32 + lk];
    #pragma unroll
    for (int mi = 0; mi < 4; mi++)
      #pragma unroll
      for (int ni = 0; ni < NI; ni++)
        acc[mi][ni] = __builtin_amdgcn_mfma_f32_16x16x32_bf16(af[mi], bfr[ni], acc[mi][ni], 0, 0, 0);
  }
  #pragma unroll
  for (int mi = 0; mi < 4; mi++)
  #pragma unroll
  for (int ni = 0; ni < NI; ni++)
  #pragma unroll
  for (int j = 0; j < 4; j++){
    int row = m0 + wrow + mi*16 + (lane >> 4) * 4 + j;   // C/D layout (m89/m91)
    int col = n0 + wcol + ni*16 + lr;
    float val = acc[mi][ni][j];
    if (MODE == 0){
      ((unsigned short*)outv)[(size_t)row * N + col] = f2bf(val);
    } else if (MODE == 1){
      ((unsigned short*)outv)[(size_t)row * N + col] = f2bf(val + bias[col]);
    } else if (MODE == 2){
      val += bias[col];
      int gl = row_off + row;
      int bb = gl / 3136, rem = gl % 3136;
      int wi = rem / 49, l = rem % 49;
      int n = ((wi >> 3) * 7 + l / 7) * 56 + (wi & 7) * 7 + l % 7;  // window reverse
      size_t idx = ((size_t)bb * 3136 + n) * CDIM + col;
      ((float*)outv)[idx] = resid[idx] + val;
    } else {
      size_t idx = (size_t)(row_off + row) * CDIM + col;
      ((float*)outv)[idx] = resid[idx] + val + bias[col];
    }
  }
}

// ---------------- Windowed attention: one wave per (window, head); writes into q-slot ----------
__global__ __launch_bounds__(64)
void attn_kern(unsigned short* __restrict__ qkv)
{
  __shared__ __align__(16) float kl[49][33], vl[49][33];
  int blk = blockIdx.x;
  int win = blk / 12, head = blk % 12;
  int t = threadIdx.x;
  size_t base = (size_t)win * 49 * N3C + head * 32;
  for (int i = t; i < 49 * 32; i += 64){
    int r = i >> 5, c = i & 31;
    size_t rb = base + (size_t)r * N3C + c;
    kl[r][c] = bf2f(qkv[rb + 384]);
    vl[r][c] = bf2f(qkv[rb + 768]);
  }
  // Q straight to registers (own row, no LDS)
  float qr[32];
  if (t < 49){
    const unsigned short* qp = &qkv[base + (size_t)t * N3C];
    #pragma unroll
    for (int g2 = 0; g2 < 4; g2++){
      bf16x8 qv = *(const bf16x8*)&qp[g2 * 8];
      #pragma unroll
      for (int d = 0; d < 8; d++) qr[g2*8 + d] = bf2f((unsigned short)qv[d]);
    }
  }
  __syncthreads();
  if (t >= 49) return;
  int wi = win & 63;
  int hq = (wi >> 3) * 7 + t / 7, wq = (wi & 7) * 7 + t % 7;
  int idq = (hq < 49 ? 0 : (hq < 53 ? 1 : 2)) * 3 + (wq < 49 ? 0 : (wq < 53 ? 1 : 2));
  const float scale = 0.17677669529663687f;
  float S[49]; float mx = -1e30f;
  #pragma unroll
  for (int j = 0; j < 49; j++){
    float s0 = 0.f, s1 = 0.f, s2 = 0.f, s3 = 0.f;
    #pragma unroll
    for (int d = 0; d < 32; d += 4){
      s0 += qr[d    ] * kl[j][d    ];
      s1 += qr[d + 1] * kl[j][d + 1];
      s2 += qr[d + 2] * kl[j][d + 2];
      s3 += qr[d + 3] * kl[j][d + 3];
    }
    int hk = (wi >> 3) * 7 + j / 7, wk = (wi & 7) * 7 + j % 7;
    int idk = (hk < 49 ? 0 : (hk < 53 ? 1 : 2)) * 3 + (wk < 49 ? 0 : (wk < 53 ? 1 : 2));
    float s = (s0 + s1 + s2 + s3) * scale + ((idq != idk) ? -100.f : 0.f);
    S[j] = s; mx = fmaxf(mx, s);
  }
  float sum = 0.f;
  #pragma unroll
  for (int j = 0; j < 49; j++){ float e = expf(S[j] - mx); S[j] = e; sum += e; }
  float inv = 1.f / sum;
  float o[32];
  #pragma unroll
  for (int d = 0; d < 32; d++) o[d] = 0.f;
  #pragma unroll
  for (int j = 0; j < 49; j++){
    float p = S[j];
    #pragma unroll
    for (int d = 0; d < 32; d++) o[d] += p * vl[j][d];
  }
  size_t ob = ((size_t)win * 49 + t) * N3C + head * 32;
  #pragma unroll
  for (int g2 = 0; g2 < 4; g2++){
    bf16x8 ovv;
    #pragma unroll
    for (int d = 0; d < 8; d++) ovv[d] = (short)f2bf(o[g2*8 + d] * inv);
    *(bf16x8*)&qkv[ob + g2*8] = ovv;
  }
}

// ---------------- Depthwise 3x3 conv + bias + exact GELU ----------------
#define CONV_T 8
__global__ __launch_bounds__(192)
void conv_gelu_kern(const unsigned short* __restrict__ x1, const float* __restrict__ kw,
                    const float* __restrict__ kb, unsigned short* __restrict__ out)
{
  __shared__ __align__(16) unsigned short wl[9][NHID];
  int tid = threadIdx.x;
  for (int i = tid; i < NHID * 9; i += 192){
    int c = i / 9, tap = i % 9;
    wl[tap][c] = f2bf(kw[i]);
  }
  __syncthreads();
  int c0 = tid * 8;
  bf16x8 wv[9];
  #pragma unroll
  for (int j = 0; j < 9; j++) wv[j] = *(const bf16x8*)&wl[j][c0];
  float bias[8];
  #pragma unroll
  for (int i = 0; i < 8; i++) bias[i] = kb[c0 + i];

  int n0 = blockIdx.x * CONV_T;
  for (int t = 0; t < CONV_T; t++){
    int n = n0 + t;
    int rem = n % 3136;
    int h = rem / 56, w = rem % 56;
    float acc[8] = {0.f,0.f,0.f,0.f,0.f,0.f,0.f,0.f};
    #pragma unroll
    for (int dh = -1; dh <= 1; dh++){
      int hh = h + dh; if (hh < 0 || hh >= 56) continue;
      #pragma unroll
      for (int dw = -1; dw <= 1; dw++){
        int ww = w + dw; if (ww < 0 || ww >= 56) continue;
        bf16x8 rv = *(const bf16x8*)&x1[((size_t)n + dh*56 + dw) * NHID + c0];
        int j = (dh + 1) * 3 + (dw + 1);
        #pragma unroll
        for (int i = 0; i < 8; i++)
          acc[i] += bf2f((unsigned short)rv[i]) * bf2f((unsigned short)wv[j][i]);
      }
    }
    size_t ob = (size_t)n * NHID + c0;
    bf16x8 ov;
    #pragma unroll
    for (int i = 0; i < 8; i++){
      float v = acc[i] + bias[i];
      ov[i] = (short)f2bf(0.5f * v * (1.f + erff(v * 0.70710678118654752f)));
    }
    *(bf16x8*)&out[ob] = ov;
  }
}

extern "C" void kernel_launch(void* const* d_in, const int* in_sizes, int n_in,
                              void* d_out, int out_size, void* d_ws, size_t ws_size,
                              hipStream_t stream)
{
  const float* x      = (const float*)d_in[0];
  const float* ln1_g  = (const float*)d_in[1];
  const float* ln1_b  = (const float*)d_in[2];
  const float* qkv_w  = (const float*)d_in[3];
  const float* proj_w = (const float*)d_in[4];
  const float* proj_b = (const float*)d_in[5];
  const float* ln2_g  = (const float*)d_in[6];
  const float* ln2_b  = (const float*)d_in[7];
  const float* fc1_w  = (const float*)d_in[8];
  const float* fc1_b  = (const float*)d_in[9];
  const float* dw_k   = (const float*)d_in[10];
  const float* dw_b   = (const float*)d_in[11];
  const float* fc2_w  = (const float*)d_in[12];
  const float* fc2_b  = (const float*)d_in[13];
  float* outp = (float*)d_out;

  const size_t WS_NEED = 90243072;
  if (ws_size < WS_NEED) return;
  char* ws = (char*)d_ws;
  unsigned short* xw   = (unsigned short*)(ws);               // 25088*384*2
  unsigned short* qkvh = (unsigned short*)(ws + 19267584);    // 25088*1152*2
  unsigned short* xn2q = (unsigned short*)(ws);               // 12544*384*2
  unsigned short* x1q  = (unsigned short*)(ws + 9633792);     // 12544*1536*2
  unsigned short* x1gq = (unsigned short*)(ws + 48168960);    // 12544*1536*2
  unsigned short* wqkv = (unsigned short*)(ws + 86704128);    // [1152][384]
  unsigned short* wproj= (unsigned short*)(ws + 87588864);    // [384][384]
  unsigned short* wfc1 = (unsigned short*)(ws + 87883776);    // [1536][384]
  unsigned short* wfc2 = (unsigned short*)(ws + 89063424);    // [384][1536]

  // 0) weights fp32 -> bf16, transposed to [N][K]
  cvtT_kern<<<dim3(12, 36), 256, 0, stream>>>(qkv_w,  wqkv, 384, 1152);
  cvtT_kern<<<dim3(12, 12), 256, 0, stream>>>(proj_w, wproj, 384, 384);
  cvtT_kern<<<dim3(12, 48), 256, 0, stream>>>(fc1_w,  wfc1, 384, 1536);
  cvtT_kern<<<dim3(48, 12), 256, 0, stream>>>(fc2_w,  wfc2, 1536, 384);

  // ---- attention path, two batch halves (25088 tokens = 512 windows each) ----
  for (int hf = 0; hf < 2; hf++){
    int ro = hf * 25088;
    ln_kern<<<25088, 64, 0, stream>>>(x, ln1_g, ln1_b, xw, ro, 1);
    gemm_kern<0,128><<<dim3(196, 9), 256, 0, stream>>>(xw, 384, wqkv, 384, 1152,
                                                       nullptr, nullptr, qkvh, 0);
    attn_kern<<<6144, 64, 0, stream>>>(qkvh);
    gemm_kern<2,64><<<dim3(196, 6), 256, 0, stream>>>(qkvh, 1152, wproj, 384, 384,
                                                      proj_b, x, outp, ro);
  }

  // ---- MLP path, four batch quarters (12544 tokens = 4 whole images each) ----
  for (int qt = 0; qt < 4; qt++){
    int ro = qt * 12544;
    ln_kern<<<12544, 64, 0, stream>>>(outp + (size_t)ro * CDIM, ln2_g, ln2_b, xn2q, 0, 0);
    gemm_kern<1,128><<<dim3(98, 12), 256, 0, stream>>>(xn2q, 384, wfc1, 384, 1536,
                                                       fc1_b, nullptr, x1q, 0);
    conv_gelu_kern<<<12544 / CONV_T, 192, 0, stream>>>(x1q, dw_k, dw_b, x1gq);
    gemm_kern<3,64><<<dim3(98, 6), 256, 0, stream>>>(x1gq, 1536, wfc2, 1536, 384,
                                                     fc2_b, outp, outp, ro);
  }
}

// Round 5
// 976.147 us; speedup vs baseline: 2.5685x; 1.1643x over previous
//
#include <hip/hip_runtime.h>

// Swin block. fp32 I/O, bf16 internal MFMA operands, fp32 trunk.
// R4: attention rewritten with MFMA (swapped S^T=K@Q^T, swizzled P/V^T LDS round-trip).

using bf16x8 = __attribute__((ext_vector_type(8))) short;
using f32x4  = __attribute__((ext_vector_type(4))) float;

#define CDIM  384
#define N3C   1152
#define NHID  1536

__device__ __forceinline__ float bf2f(unsigned short u){
  union { unsigned int i; float f; } x; x.i = ((unsigned int)u) << 16; return x.f;
}
__device__ __forceinline__ unsigned short f2bf(float f){
  union { float f; unsigned int i; } x; x.f = f;
  unsigned int r = x.i + 0x7fffu + ((x.i >> 16) & 1u);   // RNE
  return (unsigned short)(r >> 16);
}
__device__ __forceinline__ void gload16(const void* g, void* l){
  __builtin_amdgcn_global_load_lds(
      (const __attribute__((address_space(1))) unsigned int*)g,
      (__attribute__((address_space(3))) unsigned int*)l, 16, 0, 0);
}

// ---------------- transpose-convert: wt[n*K+k] = bf16(w[k*N+n]) ----------------
__global__ __launch_bounds__(256)
void cvtT_kern(const float* __restrict__ w, unsigned short* __restrict__ wt, int K, int N){
  __shared__ unsigned short t[32][33];
  int bk = blockIdx.x, bn = blockIdx.y;
  int tr = threadIdx.x >> 5, tc = threadIdx.x & 31;
  #pragma unroll
  for (int r = tr; r < 32; r += 8)
    t[r][tc] = f2bf(w[(size_t)(bk*32 + r) * N + bn*32 + tc]);
  __syncthreads();
  #pragma unroll
  for (int r = tr; r < 32; r += 8)
    wt[(size_t)(bn*32 + r) * K + bk*32 + tc] = t[tc][r];
}

// ---------------- LayerNorm (+optional roll+window-partition gather), fp32 in, bf16 out ----------
__global__ __launch_bounds__(64)
void ln_kern(const float* __restrict__ xin, const float* __restrict__ g,
             const float* __restrict__ bsh, unsigned short* __restrict__ out,
             int row_off, int do_shift)
{
  int blk = blockIdx.x, t = threadIdx.x;
  size_t src;
  if (do_shift){
    int gl = row_off + blk;
    int bb = gl / 3136, rem = gl % 3136;
    int wi = rem / 49, l = rem % 49;
    int h = (wi >> 3) * 7 + l / 7;
    int w = (wi & 7) * 7 + l % 7;
    int sh = h + 3; if (sh >= 56) sh -= 56;    // roll(-3)
    int sw = w + 3; if (sw >= 56) sw -= 56;
    src = ((size_t)bb * 3136 + sh * 56 + sw) * CDIM;
  } else {
    src = (size_t)blk * CDIM;
  }
  float v[6]; float s = 0.f;
  #pragma unroll
  for (int j = 0; j < 6; j++){ v[j] = xin[src + j*64 + t]; s += v[j]; }
  #pragma unroll
  for (int m = 32; m >= 1; m >>= 1) s += __shfl_xor(s, m);
  float mean = s * (1.f/384.f);
  float q = 0.f;
  #pragma unroll
  for (int j = 0; j < 6; j++){ float d = v[j] - mean; q += d * d; }
  #pragma unroll
  for (int m = 32; m >= 1; m >>= 1) q += __shfl_xor(q, m);
  float rstd = rsqrtf(q * (1.f/384.f) + 1e-5f);
  size_t dst = (size_t)blk * CDIM;
  #pragma unroll
  for (int j = 0; j < 6; j++){
    int c = j*64 + t;
    out[dst + c] = f2bf((v[j] - mean) * rstd * g[c] + bsh[c]);
  }
}

// ---------------- MFMA GEMM, m97-style: C[M,N] = A[M,K] @ Bt[N,K]^T ----------------
template<int MODE, int BN>
__global__ __launch_bounds__(256)
void gemm_kern(const unsigned short* __restrict__ A, int lda,
               const unsigned short* __restrict__ Bt, int K, int N,
               const float* __restrict__ bias, const float* __restrict__ resid,
               void* __restrict__ outv, int row_off)
{
  constexpr int NI = BN / 32;
  __shared__ __align__(16) unsigned short Al[128 * 32];
  __shared__ __align__(16) unsigned short Bl[BN * 32];
  int tid = threadIdx.x;
  int lane = tid & 63, wv = tid >> 6;
  int m0 = blockIdx.x * 128, n0 = blockIdx.y * BN;
  const int wrow = (wv >> 1) * 64;
  const int wcol = (wv & 1) * (BN / 2);
  const int lr = lane & 15, lk = (lane >> 4) * 8;
  f32x4 acc[4][NI] = {};
  for (int k0 = 0; k0 < K; k0 += 32){
    __syncthreads();
    #pragma unroll
    for (int i = 0; i < 2; i++){
      int c = i*256 + tid;
      gload16(&A[(size_t)(m0 + (c >> 2)) * lda + k0 + (c & 3) * 8],
              &Al[(i*256 + wv*64) * 8]);
    }
    #pragma unroll
    for (int i = 0; i < BN/64; i++){
      int c = i*256 + tid;
      gload16(&Bt[(size_t)(n0 + (c >> 2)) * K + k0 + (c & 3) * 8],
              &Bl[(i*256 + wv*64) * 8]);
    }
    __syncthreads();
    bf16x8 af[4], bfr[NI];
    #pragma unroll
    for (int mi = 0; mi < 4; mi++) af[mi] = *(const bf16x8*)&Al[(wrow + mi*16 + lr)*32 + lk];
    #pragma unroll
    for (int ni = 0; ni < NI; ni++) bfr[ni] = *(const bf16x8*)&Bl[(wcol + ni*16 + lr)*32 + lk];
    #pragma unroll
    for (int mi = 0; mi < 4; mi++)
      #pragma unroll
      for (int ni = 0; ni < NI; ni++)
        acc[mi][ni] = __builtin_amdgcn_mfma_f32_16x16x32_bf16(af[mi], bfr[ni], acc[mi][ni], 0, 0, 0);
  }
  #pragma unroll
  for (int mi = 0; mi < 4; mi++)
  #pragma unroll
  for (int ni = 0; ni < NI; ni++)
  #pragma unroll
  for (int j = 0; j < 4; j++){
    int row = m0 + wrow + mi*16 + (lane >> 4) * 4 + j;   // C/D layout (m89/m91)
    int col = n0 + wcol + ni*16 + lr;
    float val = acc[mi][ni][j];
    if (MODE == 0){
      ((unsigned short*)outv)[(size_t)row * N + col] = f2bf(val);
    } else if (MODE == 1){
      ((unsigned short*)outv)[(size_t)row * N + col] = f2bf(val + bias[col]);
    } else if (MODE == 2){
      val += bias[col];
      int gl = row_off + row;
      int bb = gl / 3136, rem = gl % 3136;
      int wi = rem / 49, l = rem % 49;
      int n = ((wi >> 3) * 7 + l / 7) * 56 + (wi & 7) * 7 + l % 7;  // window reverse
      size_t idx = ((size_t)bb * 3136 + n) * CDIM + col;
      ((float*)outv)[idx] = resid[idx] + val;
    } else {
      size_t idx = (size_t)(row_off + row) * CDIM + col;
      ((float*)outv)[idx] = resid[idx] + val + bias[col];
    }
  }
}

// ---------------- Windowed attention, MFMA version: one wave per (window, head) -------------
// S^T = K@Q^T (keys lane-local after D-layout), softmax across regs+shfl(16,32),
// P rescaled -> bf16 -> swizzled LDS slice -> A-frags; PV with swizzled V^T tile.
__global__ __launch_bounds__(64)
void attn_kern(unsigned short* __restrict__ qkv)
{
  __shared__ __align__(16) unsigned short Vt[32 * 64];   // [d][key], XOR-swizzled rows
  __shared__ __align__(16) unsigned short Pl[16 * 64];   // [q][key], XOR-swizzled rows
  __shared__ unsigned char idt[49];
  int blk = blockIdx.x;
  int win = blk / 12, head = blk % 12;
  int l = threadIdx.x;
  int g = l >> 4, q15 = l & 15;
  size_t base = (size_t)win * 49 * N3C + (size_t)head * 32;
  const unsigned short* kp = qkv + base + 384;
  const unsigned short* vp = qkv + base + 768;

  int wi = win & 63;
  if (l < 49){
    int h = (wi >> 3) * 7 + l / 7;
    int w = (wi & 7) * 7 + l % 7;
    idt[l] = (unsigned char)((h < 49 ? 0 : (h < 53 ? 1 : 2)) * 3 +
                             (w < 49 ? 0 : (w < 53 ? 1 : 2)));
  }
  // stage V^T (pad columns 49..63 duplicate key 48; they get P=0)
  #pragma unroll
  for (int it = 0; it < 4; it++){
    int c = it * 64 + l;
    int key = c >> 2, keyc = min(key, 48), d0 = (c & 3) * 8;
    bf16x8 v = *(const bf16x8*)&vp[(size_t)keyc * N3C + d0];
    #pragma unroll
    for (int j = 0; j < 8; j++){
      int d = d0 + j;
      *(unsigned short*)((char*)Vt + d * 128 + ((key * 2) ^ ((d & 7) << 4))) =
          (unsigned short)v[j];
    }
  }
  __syncthreads();

  // K A-fragments straight from global (lane&15 = key row, group = k-chunk)
  bf16x8 kf[4];
  #pragma unroll
  for (int kt = 0; kt < 4; kt++){
    int krow = min(kt * 16 + q15, 48);
    kf[kt] = *(const bf16x8*)&kp[(size_t)krow * N3C + g * 8];
  }
  // V^T B-fragments from swizzled LDS
  bf16x8 vf[2][2];
  #pragma unroll
  for (int kb = 0; kb < 2; kb++)
    #pragma unroll
    for (int nt = 0; nt < 2; nt++){
      int n = nt * 16 + q15;
      vf[kb][nt] = *(const bf16x8*)((char*)Vt + n * 128 + ((kb * 64 + g * 16) ^ ((n & 7) << 4)));
    }
  // packed region-ids for this lane's 16 keys
  unsigned int kidp[4];
  #pragma unroll
  for (int kt = 0; kt < 4; kt++){
    unsigned int p = 0;
    #pragma unroll
    for (int r = 0; r < 4; r++)
      p |= ((unsigned int)idt[min(kt * 16 + 4 * g + r, 48)]) << (8 * r);
    kidp[kt] = p;
  }

  const float scale = 0.17677669529663687f;
  const f32x4 zf = {0.f, 0.f, 0.f, 0.f};
  #pragma unroll
  for (int qt = 0; qt < 4; qt++){
    int qrow = min(qt * 16 + q15, 48);
    bf16x8 qf = *(const bf16x8*)&qkv[base + (size_t)qrow * N3C + g * 8];
    f32x4 s[4];
    #pragma unroll
    for (int kt = 0; kt < 4; kt++)
      s[kt] = __builtin_amdgcn_mfma_f32_16x16x32_bf16(kf[kt], qf, zf, 0, 0, 0);
    int qid = idt[qrow];
    float mx = -1e30f;
    #pragma unroll
    for (int kt = 0; kt < 4; kt++)
      #pragma unroll
      for (int r = 0; r < 4; r++){
        float x = s[kt][r] * scale;
        int idk = (kidp[kt] >> (8 * r)) & 255;
        x += (idk != qid) ? -100.f : 0.f;
        if (kt * 16 + 4 * g + r >= 49) x = -3.0e38f;   // padded key -> exp 0
        s[kt][r] = x;
        mx = fmaxf(mx, x);
      }
    mx = fmaxf(mx, __shfl_xor(mx, 16));
    mx = fmaxf(mx, __shfl_xor(mx, 32));
    float sum = 0.f;
    #pragma unroll
    for (int kt = 0; kt < 4; kt++)
      #pragma unroll
      for (int r = 0; r < 4; r++){
        float e = expf(s[kt][r] - mx);
        s[kt][r] = e; sum += e;
      }
    sum += __shfl_xor(sum, 16);
    sum += __shfl_xor(sum, 32);
    float inv = 1.f / sum;
    #pragma unroll
    for (int kt = 0; kt < 4; kt++){
      float e0 = s[kt][0] * inv, e1 = s[kt][1] * inv;
      float e2 = s[kt][2] * inv, e3 = s[kt][3] * inv;
      unsigned int pa, pb;
      asm("v_cvt_pk_bf16_f32 %0, %1, %2" : "=v"(pa) : "v"(e0), "v"(e1));
      asm("v_cvt_pk_bf16_f32 %0, %1, %2" : "=v"(pb) : "v"(e2), "v"(e3));
      uint2 w2; w2.x = pa; w2.y = pb;
      *(uint2*)((char*)Pl + q15 * 128 + ((kt * 32 + g * 8) ^ ((q15 & 7) << 4))) = w2;
    }
    __syncthreads();   // single wave: drains lgkm, cross-lane LDS visibility
    f32x4 o[2] = {zf, zf};
    #pragma unroll
    for (int kb = 0; kb < 2; kb++){
      bf16x8 pf = *(const bf16x8*)((char*)Pl + q15 * 128 + ((kb * 64 + g * 16) ^ ((q15 & 7) << 4)));
      #pragma unroll
      for (int nt = 0; nt < 2; nt++)
        o[nt] = __builtin_amdgcn_mfma_f32_16x16x32_bf16(pf, vf[kb][nt], o[nt], 0, 0, 0);
    }
    #pragma unroll
    for (int nt = 0; nt < 2; nt++)
      #pragma unroll
      for (int r = 0; r < 4; r++){
        int qp = qt * 16 + 4 * g + r;
        if (qp < 49)
          qkv[base + (size_t)qp * N3C + nt * 16 + q15] = f2bf(o[nt][r]);
      }
    __syncthreads();
  }
}

// ---------------- Depthwise 3x3 conv + bias + exact GELU ----------------
#define CONV_T 8
__global__ __launch_bounds__(192)
void conv_gelu_kern(const unsigned short* __restrict__ x1, const float* __restrict__ kw,
                    const float* __restrict__ kb, unsigned short* __restrict__ out)
{
  __shared__ __align__(16) unsigned short wl[9][NHID];
  int tid = threadIdx.x;
  for (int i = tid; i < NHID * 9; i += 192){
    int c = i / 9, tap = i % 9;
    wl[tap][c] = f2bf(kw[i]);
  }
  __syncthreads();
  int c0 = tid * 8;
  bf16x8 wv[9];
  #pragma unroll
  for (int j = 0; j < 9; j++) wv[j] = *(const bf16x8*)&wl[j][c0];
  float bias[8];
  #pragma unroll
  for (int i = 0; i < 8; i++) bias[i] = kb[c0 + i];

  int n0 = blockIdx.x * CONV_T;
  for (int t = 0; t < CONV_T; t++){
    int n = n0 + t;
    int rem = n % 3136;
    int h = rem / 56, w = rem % 56;
    float acc[8] = {0.f,0.f,0.f,0.f,0.f,0.f,0.f,0.f};
    #pragma unroll
    for (int dh = -1; dh <= 1; dh++){
      int hh = h + dh; if (hh < 0 || hh >= 56) continue;
      #pragma unroll
      for (int dw = -1; dw <= 1; dw++){
        int ww = w + dw; if (ww < 0 || ww >= 56) continue;
        bf16x8 rv = *(const bf16x8*)&x1[((size_t)n + dh*56 + dw) * NHID + c0];
        int j = (dh + 1) * 3 + (dw + 1);
        #pragma unroll
        for (int i = 0; i < 8; i++)
          acc[i] += bf2f((unsigned short)rv[i]) * bf2f((unsigned short)wv[j][i]);
      }
    }
    size_t ob = (size_t)n * NHID + c0;
    bf16x8 ov;
    #pragma unroll
    for (int i = 0; i < 8; i++){
      float v = acc[i] + bias[i];
      ov[i] = (short)f2bf(0.5f * v * (1.f + erff(v * 0.70710678118654752f)));
    }
    *(bf16x8*)&out[ob] = ov;
  }
}

extern "C" void kernel_launch(void* const* d_in, const int* in_sizes, int n_in,
                              void* d_out, int out_size, void* d_ws, size_t ws_size,
                              hipStream_t stream)
{
  const float* x      = (const float*)d_in[0];
  const float* ln1_g  = (const float*)d_in[1];
  const float* ln1_b  = (const float*)d_in[2];
  const float* qkv_w  = (const float*)d_in[3];
  const float* proj_w = (const float*)d_in[4];
  const float* proj_b = (const float*)d_in[5];
  const float* ln2_g  = (const float*)d_in[6];
  const float* ln2_b  = (const float*)d_in[7];
  const float* fc1_w  = (const float*)d_in[8];
  const float* fc1_b  = (const float*)d_in[9];
  const float* dw_k   = (const float*)d_in[10];
  const float* dw_b   = (const float*)d_in[11];
  const float* fc2_w  = (const float*)d_in[12];
  const float* fc2_b  = (const float*)d_in[13];
  float* outp = (float*)d_out;

  const size_t WS_NEED = 90243072;
  if (ws_size < WS_NEED) return;
  char* ws = (char*)d_ws;
  unsigned short* xw   = (unsigned short*)(ws);               // 25088*384*2
  unsigned short* qkvh = (unsigned short*)(ws + 19267584);    // 25088*1152*2
  unsigned short* xn2q = (unsigned short*)(ws);               // 12544*384*2
  unsigned short* x1q  = (unsigned short*)(ws + 9633792);     // 12544*1536*2
  unsigned short* x1gq = (unsigned short*)(ws + 48168960);    // 12544*1536*2
  unsigned short* wqkv = (unsigned short*)(ws + 86704128);    // [1152][384]
  unsigned short* wproj= (unsigned short*)(ws + 87588864);    // [384][384]
  unsigned short* wfc1 = (unsigned short*)(ws + 87883776);    // [1536][384]
  unsigned short* wfc2 = (unsigned short*)(ws + 89063424);    // [384][1536]

  cvtT_kern<<<dim3(12, 36), 256, 0, stream>>>(qkv_w,  wqkv, 384, 1152);
  cvtT_kern<<<dim3(12, 12), 256, 0, stream>>>(proj_w, wproj, 384, 384);
  cvtT_kern<<<dim3(12, 48), 256, 0, stream>>>(fc1_w,  wfc1, 384, 1536);
  cvtT_kern<<<dim3(48, 12), 256, 0, stream>>>(fc2_w,  wfc2, 1536, 384);

  // ---- attention path, two batch halves (25088 tokens = 512 windows each) ----
  for (int hf = 0; hf < 2; hf++){
    int ro = hf * 25088;
    ln_kern<<<25088, 64, 0, stream>>>(x, ln1_g, ln1_b, xw, ro, 1);
    gemm_kern<0,128><<<dim3(196, 9), 256, 0, stream>>>(xw, 384, wqkv, 384, 1152,
                                                       nullptr, nullptr, qkvh, 0);
    attn_kern<<<6144, 64, 0, stream>>>(qkvh);
    gemm_kern<2,64><<<dim3(196, 6), 256, 0, stream>>>(qkvh, 1152, wproj, 384, 384,
                                                      proj_b, x, outp, ro);
  }

  // ---- MLP path, four batch quarters (12544 tokens = 4 whole images each) ----
  for (int qt = 0; qt < 4; qt++){
    int ro = qt * 12544;
    ln_kern<<<12544, 64, 0, stream>>>(outp + (size_t)ro * CDIM, ln2_g, ln2_b, xn2q, 0, 0);
    gemm_kern<1,128><<<dim3(98, 12), 256, 0, stream>>>(xn2q, 384, wfc1, 384, 1536,
                                                       fc1_b, nullptr, x1q, 0);
    conv_gelu_kern<<<12544 / CONV_T, 192, 0, stream>>>(x1q, dw_k, dw_b, x1gq);
    gemm_kern<3,64><<<dim3(98, 6), 256, 0, stream>>>(x1gq, 1536, wfc2, 1536, 384,
                                                     fc2_b, outp, outp, ro);
  }
}

// Round 6
// 935.018 us; speedup vs baseline: 2.6815x; 1.0440x over previous
//
#include <hip/hip_runtime.h>

// Swin block. fp32 I/O, bf16 internal MFMA operands, fp32 trunk.
// R5: conv_gelu LDS removed — weights pre-transposed to [tap][ch] bf16 in global,
//     loaded per-thread as 16B fragments (L2 broadcast). No bank conflicts, no LDS cap.

using bf16x8 = __attribute__((ext_vector_type(8))) short;
using f32x4  = __attribute__((ext_vector_type(4))) float;

#define CDIM  384
#define N3C   1152
#define NHID  1536

__device__ __forceinline__ float bf2f(unsigned short u){
  union { unsigned int i; float f; } x; x.i = ((unsigned int)u) << 16; return x.f;
}
__device__ __forceinline__ unsigned short f2bf(float f){
  union { float f; unsigned int i; } x; x.f = f;
  unsigned int r = x.i + 0x7fffu + ((x.i >> 16) & 1u);   // RNE
  return (unsigned short)(r >> 16);
}
__device__ __forceinline__ void gload16(const void* g, void* l){
  __builtin_amdgcn_global_load_lds(
      (const __attribute__((address_space(1))) unsigned int*)g,
      (__attribute__((address_space(3))) unsigned int*)l, 16, 0, 0);
}

// ---------------- transpose-convert: wt[n*K+k] = bf16(w[k*N+n]) ----------------
__global__ __launch_bounds__(256)
void cvtT_kern(const float* __restrict__ w, unsigned short* __restrict__ wt, int K, int N){
  __shared__ unsigned short t[32][33];
  int bk = blockIdx.x, bn = blockIdx.y;
  int tr = threadIdx.x >> 5, tc = threadIdx.x & 31;
  #pragma unroll
  for (int r = tr; r < 32; r += 8)
    t[r][tc] = f2bf(w[(size_t)(bk*32 + r) * N + bn*32 + tc]);
  __syncthreads();
  #pragma unroll
  for (int r = tr; r < 32; r += 8)
    wt[(size_t)(bn*32 + r) * K + bk*32 + tc] = t[tc][r];
}

// ---------------- dw weights: [1536][9] fp32 -> [9][1536] bf16 ----------------
__global__ __launch_bounds__(256)
void cvtDW_kern(const float* __restrict__ k, unsigned short* __restrict__ wt){
  int i = blockIdx.x * 256 + threadIdx.x;
  if (i < NHID * 9){
    int c = i / 9, tap = i % 9;
    wt[tap * NHID + c] = f2bf(k[i]);
  }
}

// ---------------- LayerNorm (+optional roll+window-partition gather), fp32 in, bf16 out ----------
__global__ __launch_bounds__(64)
void ln_kern(const float* __restrict__ xin, const float* __restrict__ g,
             const float* __restrict__ bsh, unsigned short* __restrict__ out,
             int row_off, int do_shift)
{
  int blk = blockIdx.x, t = threadIdx.x;
  size_t src;
  if (do_shift){
    int gl = row_off + blk;
    int bb = gl / 3136, rem = gl % 3136;
    int wi = rem / 49, l = rem % 49;
    int h = (wi >> 3) * 7 + l / 7;
    int w = (wi & 7) * 7 + l % 7;
    int sh = h + 3; if (sh >= 56) sh -= 56;    // roll(-3)
    int sw = w + 3; if (sw >= 56) sw -= 56;
    src = ((size_t)bb * 3136 + sh * 56 + sw) * CDIM;
  } else {
    src = (size_t)blk * CDIM;
  }
  float v[6]; float s = 0.f;
  #pragma unroll
  for (int j = 0; j < 6; j++){ v[j] = xin[src + j*64 + t]; s += v[j]; }
  #pragma unroll
  for (int m = 32; m >= 1; m >>= 1) s += __shfl_xor(s, m);
  float mean = s * (1.f/384.f);
  float q = 0.f;
  #pragma unroll
  for (int j = 0; j < 6; j++){ float d = v[j] - mean; q += d * d; }
  #pragma unroll
  for (int m = 32; m >= 1; m >>= 1) q += __shfl_xor(q, m);
  float rstd = rsqrtf(q * (1.f/384.f) + 1e-5f);
  size_t dst = (size_t)blk * CDIM;
  #pragma unroll
  for (int j = 0; j < 6; j++){
    int c = j*64 + t;
    out[dst + c] = f2bf((v[j] - mean) * rstd * g[c] + bsh[c]);
  }
}

// ---------------- MFMA GEMM, m97-style: C[M,N] = A[M,K] @ Bt[N,K]^T ----------------
template<int MODE, int BN>
__global__ __launch_bounds__(256)
void gemm_kern(const unsigned short* __restrict__ A, int lda,
               const unsigned short* __restrict__ Bt, int K, int N,
               const float* __restrict__ bias, const float* __restrict__ resid,
               void* __restrict__ outv, int row_off)
{
  constexpr int NI = BN / 32;
  __shared__ __align__(16) unsigned short Al[128 * 32];
  __shared__ __align__(16) unsigned short Bl[BN * 32];
  int tid = threadIdx.x;
  int lane = tid & 63, wv = tid >> 6;
  int m0 = blockIdx.x * 128, n0 = blockIdx.y * BN;
  const int wrow = (wv >> 1) * 64;
  const int wcol = (wv & 1) * (BN / 2);
  const int lr = lane & 15, lk = (lane >> 4) * 8;
  f32x4 acc[4][NI] = {};
  for (int k0 = 0; k0 < K; k0 += 32){
    __syncthreads();
    #pragma unroll
    for (int i = 0; i < 2; i++){
      int c = i*256 + tid;
      gload16(&A[(size_t)(m0 + (c >> 2)) * lda + k0 + (c & 3) * 8],
              &Al[(i*256 + wv*64) * 8]);
    }
    #pragma unroll
    for (int i = 0; i < BN/64; i++){
      int c = i*256 + tid;
      gload16(&Bt[(size_t)(n0 + (c >> 2)) * K + k0 + (c & 3) * 8],
              &Bl[(i*256 + wv*64) * 8]);
    }
    __syncthreads();
    bf16x8 af[4], bfr[NI];
    #pragma unroll
    for (int mi = 0; mi < 4; mi++) af[mi] = *(const bf16x8*)&Al[(wrow + mi*16 + lr)*32 + lk];
    #pragma unroll
    for (int ni = 0; ni < NI; ni++) bfr[ni] = *(const bf16x8*)&Bl[(wcol + ni*16 + lr)*32 + lk];
    #pragma unroll
    for (int mi = 0; mi < 4; mi++)
      #pragma unroll
      for (int ni = 0; ni < NI; ni++)
        acc[mi][ni] = __builtin_amdgcn_mfma_f32_16x16x32_bf16(af[mi], bfr[ni], acc[mi][ni], 0, 0, 0);
  }
  #pragma unroll
  for (int mi = 0; mi < 4; mi++)
  #pragma unroll
  for (int ni = 0; ni < NI; ni++)
  #pragma unroll
  for (int j = 0; j < 4; j++){
    int row = m0 + wrow + mi*16 + (lane >> 4) * 4 + j;   // C/D layout (m89/m91)
    int col = n0 + wcol + ni*16 + lr;
    float val = acc[mi][ni][j];
    if (MODE == 0){
      ((unsigned short*)outv)[(size_t)row * N + col] = f2bf(val);
    } else if (MODE == 1){
      ((unsigned short*)outv)[(size_t)row * N + col] = f2bf(val + bias[col]);
    } else if (MODE == 2){
      val += bias[col];
      int gl = row_off + row;
      int bb = gl / 3136, rem = gl % 3136;
      int wi = rem / 49, l = rem % 49;
      int n = ((wi >> 3) * 7 + l / 7) * 56 + (wi & 7) * 7 + l % 7;  // window reverse
      size_t idx = ((size_t)bb * 3136 + n) * CDIM + col;
      ((float*)outv)[idx] = resid[idx] + val;
    } else {
      size_t idx = (size_t)(row_off + row) * CDIM + col;
      ((float*)outv)[idx] = resid[idx] + val + bias[col];
    }
  }
}

// ---------------- Windowed attention, MFMA version: one wave per (window, head) -------------
__global__ __launch_bounds__(64)
void attn_kern(unsigned short* __restrict__ qkv)
{
  __shared__ __align__(16) unsigned short Vt[32 * 64];   // [d][key], XOR-swizzled rows
  __shared__ __align__(16) unsigned short Pl[16 * 64];   // [q][key], XOR-swizzled rows
  __shared__ unsigned char idt[49];
  int blk = blockIdx.x;
  int win = blk / 12, head = blk % 12;
  int l = threadIdx.x;
  int g = l >> 4, q15 = l & 15;
  size_t base = (size_t)win * 49 * N3C + (size_t)head * 32;
  const unsigned short* kp = qkv + base + 384;
  const unsigned short* vp = qkv + base + 768;

  int wi = win & 63;
  if (l < 49){
    int h = (wi >> 3) * 7 + l / 7;
    int w = (wi & 7) * 7 + l % 7;
    idt[l] = (unsigned char)((h < 49 ? 0 : (h < 53 ? 1 : 2)) * 3 +
                             (w < 49 ? 0 : (w < 53 ? 1 : 2)));
  }
  #pragma unroll
  for (int it = 0; it < 4; it++){
    int c = it * 64 + l;
    int key = c >> 2, keyc = min(key, 48), d0 = (c & 3) * 8;
    bf16x8 v = *(const bf16x8*)&vp[(size_t)keyc * N3C + d0];
    #pragma unroll
    for (int j = 0; j < 8; j++){
      int d = d0 + j;
      *(unsigned short*)((char*)Vt + d * 128 + ((key * 2) ^ ((d & 7) << 4))) =
          (unsigned short)v[j];
    }
  }
  __syncthreads();

  bf16x8 kf[4];
  #pragma unroll
  for (int kt = 0; kt < 4; kt++){
    int krow = min(kt * 16 + q15, 48);
    kf[kt] = *(const bf16x8*)&kp[(size_t)krow * N3C + g * 8];
  }
  bf16x8 vf[2][2];
  #pragma unroll
  for (int kb = 0; kb < 2; kb++)
    #pragma unroll
    for (int nt = 0; nt < 2; nt++){
      int n = nt * 16 + q15;
      vf[kb][nt] = *(const bf16x8*)((char*)Vt + n * 128 + ((kb * 64 + g * 16) ^ ((n & 7) << 4)));
    }
  unsigned int kidp[4];
  #pragma unroll
  for (int kt = 0; kt < 4; kt++){
    unsigned int p = 0;
    #pragma unroll
    for (int r = 0; r < 4; r++)
      p |= ((unsigned int)idt[min(kt * 16 + 4 * g + r, 48)]) << (8 * r);
    kidp[kt] = p;
  }

  const float scale = 0.17677669529663687f;
  const f32x4 zf = {0.f, 0.f, 0.f, 0.f};
  #pragma unroll
  for (int qt = 0; qt < 4; qt++){
    int qrow = min(qt * 16 + q15, 48);
    bf16x8 qf = *(const bf16x8*)&qkv[base + (size_t)qrow * N3C + g * 8];
    f32x4 s[4];
    #pragma unroll
    for (int kt = 0; kt < 4; kt++)
      s[kt] = __builtin_amdgcn_mfma_f32_16x16x32_bf16(kf[kt], qf, zf, 0, 0, 0);
    int qid = idt[qrow];
    float mx = -1e30f;
    #pragma unroll
    for (int kt = 0; kt < 4; kt++)
      #pragma unroll
      for (int r = 0; r < 4; r++){
        float x = s[kt][r] * scale;
        int idk = (kidp[kt] >> (8 * r)) & 255;
        x += (idk != qid) ? -100.f : 0.f;
        if (kt * 16 + 4 * g + r >= 49) x = -3.0e38f;   // padded key -> exp 0
        s[kt][r] = x;
        mx = fmaxf(mx, x);
      }
    mx = fmaxf(mx, __shfl_xor(mx, 16));
    mx = fmaxf(mx, __shfl_xor(mx, 32));
    float sum = 0.f;
    #pragma unroll
    for (int kt = 0; kt < 4; kt++)
      #pragma unroll
      for (int r = 0; r < 4; r++){
        float e = expf(s[kt][r] - mx);
        s[kt][r] = e; sum += e;
      }
    sum += __shfl_xor(sum, 16);
    sum += __shfl_xor(sum, 32);
    float inv = 1.f / sum;
    #pragma unroll
    for (int kt = 0; kt < 4; kt++){
      float e0 = s[kt][0] * inv, e1 = s[kt][1] * inv;
      float e2 = s[kt][2] * inv, e3 = s[kt][3] * inv;
      unsigned int pa, pb;
      asm("v_cvt_pk_bf16_f32 %0, %1, %2" : "=v"(pa) : "v"(e0), "v"(e1));
      asm("v_cvt_pk_bf16_f32 %0, %1, %2" : "=v"(pb) : "v"(e2), "v"(e3));
      uint2 w2; w2.x = pa; w2.y = pb;
      *(uint2*)((char*)Pl + q15 * 128 + ((kt * 32 + g * 8) ^ ((q15 & 7) << 4))) = w2;
    }
    __syncthreads();
    f32x4 o[2] = {zf, zf};
    #pragma unroll
    for (int kb = 0; kb < 2; kb++){
      bf16x8 pf = *(const bf16x8*)((char*)Pl + q15 * 128 + ((kb * 64 + g * 16) ^ ((q15 & 7) << 4)));
      #pragma unroll
      for (int nt = 0; nt < 2; nt++)
        o[nt] = __builtin_amdgcn_mfma_f32_16x16x32_bf16(pf, vf[kb][nt], o[nt], 0, 0, 0);
    }
    #pragma unroll
    for (int nt = 0; nt < 2; nt++)
      #pragma unroll
      for (int r = 0; r < 4; r++){
        int qp = qt * 16 + 4 * g + r;
        if (qp < 49)
          qkv[base + (size_t)qp * N3C + nt * 16 + q15] = f2bf(o[nt][r]);
      }
    __syncthreads();
  }
}

// ---------------- Depthwise 3x3 conv + bias + exact GELU (no LDS) ----------------
#define CONV_T 8
__global__ __launch_bounds__(192)
void conv_gelu_kern(const unsigned short* __restrict__ x1, const unsigned short* __restrict__ wt,
                    const float* __restrict__ kb, unsigned short* __restrict__ out)
{
  int tid = threadIdx.x;
  int c0 = tid * 8;
  bf16x8 wv[9];
  #pragma unroll
  for (int j = 0; j < 9; j++) wv[j] = *(const bf16x8*)&wt[j * NHID + c0];
  float4 bA = *(const float4*)&kb[c0];
  float4 bB = *(const float4*)&kb[c0 + 4];
  float bias[8] = {bA.x, bA.y, bA.z, bA.w, bB.x, bB.y, bB.z, bB.w};

  int n0 = blockIdx.x * CONV_T;
  for (int t = 0; t < CONV_T; t++){
    int n = n0 + t;                             // wave-uniform
    int rem = n % 3136;
    int h = rem / 56, w = rem % 56;
    float acc[8] = {0.f,0.f,0.f,0.f,0.f,0.f,0.f,0.f};
    #pragma unroll
    for (int dh = -1; dh <= 1; dh++){
      int hh = h + dh; if (hh < 0 || hh >= 56) continue;
      #pragma unroll
      for (int dw = -1; dw <= 1; dw++){
        int ww = w + dw; if (ww < 0 || ww >= 56) continue;
        bf16x8 rv = *(const bf16x8*)&x1[((size_t)n + dh*56 + dw) * NHID + c0];
        int j = (dh + 1) * 3 + (dw + 1);
        #pragma unroll
        for (int i = 0; i < 8; i++)
          acc[i] += bf2f((unsigned short)rv[i]) * bf2f((unsigned short)wv[j][i]);
      }
    }
    size_t ob = (size_t)n * NHID + c0;
    bf16x8 ov;
    #pragma unroll
    for (int i = 0; i < 8; i++){
      float v = acc[i] + bias[i];
      ov[i] = (short)f2bf(0.5f * v * (1.f + erff(v * 0.70710678118654752f)));
    }
    *(bf16x8*)&out[ob] = ov;
  }
}

extern "C" void kernel_launch(void* const* d_in, const int* in_sizes, int n_in,
                              void* d_out, int out_size, void* d_ws, size_t ws_size,
                              hipStream_t stream)
{
  const float* x      = (const float*)d_in[0];
  const float* ln1_g  = (const float*)d_in[1];
  const float* ln1_b  = (const float*)d_in[2];
  const float* qkv_w  = (const float*)d_in[3];
  const float* proj_w = (const float*)d_in[4];
  const float* proj_b = (const float*)d_in[5];
  const float* ln2_g  = (const float*)d_in[6];
  const float* ln2_b  = (const float*)d_in[7];
  const float* fc1_w  = (const float*)d_in[8];
  const float* fc1_b  = (const float*)d_in[9];
  const float* dw_k   = (const float*)d_in[10];
  const float* dw_b   = (const float*)d_in[11];
  const float* fc2_w  = (const float*)d_in[12];
  const float* fc2_b  = (const float*)d_in[13];
  float* outp = (float*)d_out;

  const size_t WS_NEED = 90270720;
  if (ws_size < WS_NEED) return;
  char* ws = (char*)d_ws;
  unsigned short* xw   = (unsigned short*)(ws);               // 25088*384*2
  unsigned short* qkvh = (unsigned short*)(ws + 19267584);    // 25088*1152*2
  unsigned short* xn2q = (unsigned short*)(ws);               // 12544*384*2
  unsigned short* x1q  = (unsigned short*)(ws + 9633792);     // 12544*1536*2
  unsigned short* x1gq = (unsigned short*)(ws + 48168960);    // 12544*1536*2
  unsigned short* wqkv = (unsigned short*)(ws + 86704128);    // [1152][384]
  unsigned short* wproj= (unsigned short*)(ws + 87588864);    // [384][384]
  unsigned short* wfc1 = (unsigned short*)(ws + 87883776);    // [1536][384]
  unsigned short* wfc2 = (unsigned short*)(ws + 89063424);    // [384][1536]
  unsigned short* wdw  = (unsigned short*)(ws + 90243072);    // [9][1536]

  cvtT_kern<<<dim3(12, 36), 256, 0, stream>>>(qkv_w,  wqkv, 384, 1152);
  cvtT_kern<<<dim3(12, 12), 256, 0, stream>>>(proj_w, wproj, 384, 384);
  cvtT_kern<<<dim3(12, 48), 256, 0, stream>>>(fc1_w,  wfc1, 384, 1536);
  cvtT_kern<<<dim3(48, 12), 256, 0, stream>>>(fc2_w,  wfc2, 1536, 384);
  cvtDW_kern<<<(NHID*9 + 255)/256, 256, 0, stream>>>(dw_k, wdw);

  // ---- attention path, two batch halves (25088 tokens = 512 windows each) ----
  for (int hf = 0; hf < 2; hf++){
    int ro = hf * 25088;
    ln_kern<<<25088, 64, 0, stream>>>(x, ln1_g, ln1_b, xw, ro, 1);
    gemm_kern<0,128><<<dim3(196, 9), 256, 0, stream>>>(xw, 384, wqkv, 384, 1152,
                                                       nullptr, nullptr, qkvh, 0);
    attn_kern<<<6144, 64, 0, stream>>>(qkvh);
    gemm_kern<2,64><<<dim3(196, 6), 256, 0, stream>>>(qkvh, 1152, wproj, 384, 384,
                                                      proj_b, x, outp, ro);
  }

  // ---- MLP path, four batch quarters (12544 tokens = 4 whole images each) ----
  for (int qt = 0; qt < 4; qt++){
    int ro = qt * 12544;
    ln_kern<<<12544, 64, 0, stream>>>(outp + (size_t)ro * CDIM, ln2_g, ln2_b, xn2q, 0, 0);
    gemm_kern<1,128><<<dim3(98, 12), 256, 0, stream>>>(xn2q, 384, wfc1, 384, 1536,
                                                       fc1_b, nullptr, x1q, 0);
    conv_gelu_kern<<<12544 / CONV_T, 192, 0, stream>>>(x1q, wdw, dw_b, x1gq);
    gemm_kern<3,64><<<dim3(98, 6), 256, 0, stream>>>(x1gq, 1536, wfc2, 1536, 384,
                                                     fc2_b, outp, outp, ro);
  }
}

// Round 7
// 785.362 us; speedup vs baseline: 3.1925x; 1.1906x over previous
//
#include <hip/hip_runtime.h>

// Swin block. fp32 I/O, bf16 internal MFMA operands, fp32 trunk.
// R6: conv_gelu restructured — 4ch/thread (384-thr blocks, low VGPR, high occupancy),
//     tanh-GELU (~7 VALU) instead of erff, cvt_pk bf16 stores.

using bf16x8 = __attribute__((ext_vector_type(8))) short;
using f32x4  = __attribute__((ext_vector_type(4))) float;

#define CDIM  384
#define N3C   1152
#define NHID  1536

__device__ __forceinline__ float bf2f(unsigned short u){
  union { unsigned int i; float f; } x; x.i = ((unsigned int)u) << 16; return x.f;
}
__device__ __forceinline__ unsigned short f2bf(float f){
  union { float f; unsigned int i; } x; x.f = f;
  unsigned int r = x.i + 0x7fffu + ((x.i >> 16) & 1u);   // RNE
  return (unsigned short)(r >> 16);
}
__device__ __forceinline__ void gload16(const void* g, void* l){
  __builtin_amdgcn_global_load_lds(
      (const __attribute__((address_space(1))) unsigned int*)g,
      (__attribute__((address_space(3))) unsigned int*)l, 16, 0, 0);
}

// ---------------- transpose-convert: wt[n*K+k] = bf16(w[k*N+n]) ----------------
__global__ __launch_bounds__(256)
void cvtT_kern(const float* __restrict__ w, unsigned short* __restrict__ wt, int K, int N){
  __shared__ unsigned short t[32][33];
  int bk = blockIdx.x, bn = blockIdx.y;
  int tr = threadIdx.x >> 5, tc = threadIdx.x & 31;
  #pragma unroll
  for (int r = tr; r < 32; r += 8)
    t[r][tc] = f2bf(w[(size_t)(bk*32 + r) * N + bn*32 + tc]);
  __syncthreads();
  #pragma unroll
  for (int r = tr; r < 32; r += 8)
    wt[(size_t)(bn*32 + r) * K + bk*32 + tc] = t[tc][r];
}

// ---------------- dw weights: [1536][9] fp32 -> [9][1536] bf16 ----------------
__global__ __launch_bounds__(256)
void cvtDW_kern(const float* __restrict__ k, unsigned short* __restrict__ wt){
  int i = blockIdx.x * 256 + threadIdx.x;
  if (i < NHID * 9){
    int c = i / 9, tap = i % 9;
    wt[tap * NHID + c] = f2bf(k[i]);
  }
}

// ---------------- LayerNorm (+optional roll+window-partition gather), fp32 in, bf16 out ----------
__global__ __launch_bounds__(64)
void ln_kern(const float* __restrict__ xin, const float* __restrict__ g,
             const float* __restrict__ bsh, unsigned short* __restrict__ out,
             int row_off, int do_shift)
{
  int blk = blockIdx.x, t = threadIdx.x;
  size_t src;
  if (do_shift){
    int gl = row_off + blk;
    int bb = gl / 3136, rem = gl % 3136;
    int wi = rem / 49, l = rem % 49;
    int h = (wi >> 3) * 7 + l / 7;
    int w = (wi & 7) * 7 + l % 7;
    int sh = h + 3; if (sh >= 56) sh -= 56;    // roll(-3)
    int sw = w + 3; if (sw >= 56) sw -= 56;
    src = ((size_t)bb * 3136 + sh * 56 + sw) * CDIM;
  } else {
    src = (size_t)blk * CDIM;
  }
  float v[6]; float s = 0.f;
  #pragma unroll
  for (int j = 0; j < 6; j++){ v[j] = xin[src + j*64 + t]; s += v[j]; }
  #pragma unroll
  for (int m = 32; m >= 1; m >>= 1) s += __shfl_xor(s, m);
  float mean = s * (1.f/384.f);
  float q = 0.f;
  #pragma unroll
  for (int j = 0; j < 6; j++){ float d = v[j] - mean; q += d * d; }
  #pragma unroll
  for (int m = 32; m >= 1; m >>= 1) q += __shfl_xor(q, m);
  float rstd = rsqrtf(q * (1.f/384.f) + 1e-5f);
  size_t dst = (size_t)blk * CDIM;
  #pragma unroll
  for (int j = 0; j < 6; j++){
    int c = j*64 + t;
    out[dst + c] = f2bf((v[j] - mean) * rstd * g[c] + bsh[c]);
  }
}

// ---------------- MFMA GEMM, m97-style: C[M,N] = A[M,K] @ Bt[N,K]^T ----------------
template<int MODE, int BN>
__global__ __launch_bounds__(256)
void gemm_kern(const unsigned short* __restrict__ A, int lda,
               const unsigned short* __restrict__ Bt, int K, int N,
               const float* __restrict__ bias, const float* __restrict__ resid,
               void* __restrict__ outv, int row_off)
{
  constexpr int NI = BN / 32;
  __shared__ __align__(16) unsigned short Al[128 * 32];
  __shared__ __align__(16) unsigned short Bl[BN * 32];
  int tid = threadIdx.x;
  int lane = tid & 63, wv = tid >> 6;
  int m0 = blockIdx.x * 128, n0 = blockIdx.y * BN;
  const int wrow = (wv >> 1) * 64;
  const int wcol = (wv & 1) * (BN / 2);
  const int lr = lane & 15, lk = (lane >> 4) * 8;
  f32x4 acc[4][NI] = {};
  for (int k0 = 0; k0 < K; k0 += 32){
    __syncthreads();
    #pragma unroll
    for (int i = 0; i < 2; i++){
      int c = i*256 + tid;
      gload16(&A[(size_t)(m0 + (c >> 2)) * lda + k0 + (c & 3) * 8],
              &Al[(i*256 + wv*64) * 8]);
    }
    #pragma unroll
    for (int i = 0; i < BN/64; i++){
      int c = i*256 + tid;
      gload16(&Bt[(size_t)(n0 + (c >> 2)) * K + k0 + (c & 3) * 8],
              &Bl[(i*256 + wv*64) * 8]);
    }
    __syncthreads();
    bf16x8 af[4], bfr[NI];
    #pragma unroll
    for (int mi = 0; mi < 4; mi++) af[mi] = *(const bf16x8*)&Al[(wrow + mi*16 + lr)*32 + lk];
    #pragma unroll
    for (int ni = 0; ni < NI; ni++) bfr[ni] = *(const bf16x8*)&Bl[(wcol + ni*16 + lr)*32 + lk];
    #pragma unroll
    for (int mi = 0; mi < 4; mi++)
      #pragma unroll
      for (int ni = 0; ni < NI; ni++)
        acc[mi][ni] = __builtin_amdgcn_mfma_f32_16x16x32_bf16(af[mi], bfr[ni], acc[mi][ni], 0, 0, 0);
  }
  #pragma unroll
  for (int mi = 0; mi < 4; mi++)
  #pragma unroll
  for (int ni = 0; ni < NI; ni++)
  #pragma unroll
  for (int j = 0; j < 4; j++){
    int row = m0 + wrow + mi*16 + (lane >> 4) * 4 + j;   // C/D layout (m89/m91)
    int col = n0 + wcol + ni*16 + lr;
    float val = acc[mi][ni][j];
    if (MODE == 0){
      ((unsigned short*)outv)[(size_t)row * N + col] = f2bf(val);
    } else if (MODE == 1){
      ((unsigned short*)outv)[(size_t)row * N + col] = f2bf(val + bias[col]);
    } else if (MODE == 2){
      val += bias[col];
      int gl = row_off + row;
      int bb = gl / 3136, rem = gl % 3136;
      int wi = rem / 49, l = rem % 49;
      int n = ((wi >> 3) * 7 + l / 7) * 56 + (wi & 7) * 7 + l % 7;  // window reverse
      size_t idx = ((size_t)bb * 3136 + n) * CDIM + col;
      ((float*)outv)[idx] = resid[idx] + val;
    } else {
      size_t idx = (size_t)(row_off + row) * CDIM + col;
      ((float*)outv)[idx] = resid[idx] + val + bias[col];
    }
  }
}

// ---------------- Windowed attention, MFMA version: one wave per (window, head) -------------
__global__ __launch_bounds__(64)
void attn_kern(unsigned short* __restrict__ qkv)
{
  __shared__ __align__(16) unsigned short Vt[32 * 64];   // [d][key], XOR-swizzled rows
  __shared__ __align__(16) unsigned short Pl[16 * 64];   // [q][key], XOR-swizzled rows
  __shared__ unsigned char idt[49];
  int blk = blockIdx.x;
  int win = blk / 12, head = blk % 12;
  int l = threadIdx.x;
  int g = l >> 4, q15 = l & 15;
  size_t base = (size_t)win * 49 * N3C + (size_t)head * 32;
  const unsigned short* kp = qkv + base + 384;
  const unsigned short* vp = qkv + base + 768;

  int wi = win & 63;
  if (l < 49){
    int h = (wi >> 3) * 7 + l / 7;
    int w = (wi & 7) * 7 + l % 7;
    idt[l] = (unsigned char)((h < 49 ? 0 : (h < 53 ? 1 : 2)) * 3 +
                             (w < 49 ? 0 : (w < 53 ? 1 : 2)));
  }
  #pragma unroll
  for (int it = 0; it < 4; it++){
    int c = it * 64 + l;
    int key = c >> 2, keyc = min(key, 48), d0 = (c & 3) * 8;
    bf16x8 v = *(const bf16x8*)&vp[(size_t)keyc * N3C + d0];
    #pragma unroll
    for (int j = 0; j < 8; j++){
      int d = d0 + j;
      *(unsigned short*)((char*)Vt + d * 128 + ((key * 2) ^ ((d & 7) << 4))) =
          (unsigned short)v[j];
    }
  }
  __syncthreads();

  bf16x8 kf[4];
  #pragma unroll
  for (int kt = 0; kt < 4; kt++){
    int krow = min(kt * 16 + q15, 48);
    kf[kt] = *(const bf16x8*)&kp[(size_t)krow * N3C + g * 8];
  }
  bf16x8 vf[2][2];
  #pragma unroll
  for (int kb = 0; kb < 2; kb++)
    #pragma unroll
    for (int nt = 0; nt < 2; nt++){
      int n = nt * 16 + q15;
      vf[kb][nt] = *(const bf16x8*)((char*)Vt + n * 128 + ((kb * 64 + g * 16) ^ ((n & 7) << 4)));
    }
  unsigned int kidp[4];
  #pragma unroll
  for (int kt = 0; kt < 4; kt++){
    unsigned int p = 0;
    #pragma unroll
    for (int r = 0; r < 4; r++)
      p |= ((unsigned int)idt[min(kt * 16 + 4 * g + r, 48)]) << (8 * r);
    kidp[kt] = p;
  }

  const float scale = 0.17677669529663687f;
  const f32x4 zf = {0.f, 0.f, 0.f, 0.f};
  #pragma unroll
  for (int qt = 0; qt < 4; qt++){
    int qrow = min(qt * 16 + q15, 48);
    bf16x8 qf = *(const bf16x8*)&qkv[base + (size_t)qrow * N3C + g * 8];
    f32x4 s[4];
    #pragma unroll
    for (int kt = 0; kt < 4; kt++)
      s[kt] = __builtin_amdgcn_mfma_f32_16x16x32_bf16(kf[kt], qf, zf, 0, 0, 0);
    int qid = idt[qrow];
    float mx = -1e30f;
    #pragma unroll
    for (int kt = 0; kt < 4; kt++)
      #pragma unroll
      for (int r = 0; r < 4; r++){
        float x = s[kt][r] * scale;
        int idk = (kidp[kt] >> (8 * r)) & 255;
        x += (idk != qid) ? -100.f : 0.f;
        if (kt * 16 + 4 * g + r >= 49) x = -3.0e38f;   // padded key -> exp 0
        s[kt][r] = x;
        mx = fmaxf(mx, x);
      }
    mx = fmaxf(mx, __shfl_xor(mx, 16));
    mx = fmaxf(mx, __shfl_xor(mx, 32));
    float sum = 0.f;
    #pragma unroll
    for (int kt = 0; kt < 4; kt++)
      #pragma unroll
      for (int r = 0; r < 4; r++){
        float e = expf(s[kt][r] - mx);
        s[kt][r] = e; sum += e;
      }
    sum += __shfl_xor(sum, 16);
    sum += __shfl_xor(sum, 32);
    float inv = 1.f / sum;
    #pragma unroll
    for (int kt = 0; kt < 4; kt++){
      float e0 = s[kt][0] * inv, e1 = s[kt][1] * inv;
      float e2 = s[kt][2] * inv, e3 = s[kt][3] * inv;
      unsigned int pa, pb;
      asm("v_cvt_pk_bf16_f32 %0, %1, %2" : "=v"(pa) : "v"(e0), "v"(e1));
      asm("v_cvt_pk_bf16_f32 %0, %1, %2" : "=v"(pb) : "v"(e2), "v"(e3));
      uint2 w2; w2.x = pa; w2.y = pb;
      *(uint2*)((char*)Pl + q15 * 128 + ((kt * 32 + g * 8) ^ ((q15 & 7) << 4))) = w2;
    }
    __syncthreads();
    f32x4 o[2] = {zf, zf};
    #pragma unroll
    for (int kb = 0; kb < 2; kb++){
      bf16x8 pf = *(const bf16x8*)((char*)Pl + q15 * 128 + ((kb * 64 + g * 16) ^ ((q15 & 7) << 4)));
      #pragma unroll
      for (int nt = 0; nt < 2; nt++)
        o[nt] = __builtin_amdgcn_mfma_f32_16x16x32_bf16(pf, vf[kb][nt], o[nt], 0, 0, 0);
    }
    #pragma unroll
    for (int nt = 0; nt < 2; nt++)
      #pragma unroll
      for (int r = 0; r < 4; r++){
        int qp = qt * 16 + 4 * g + r;
        if (qp < 49)
          qkv[base + (size_t)qp * N3C + nt * 16 + q15] = f2bf(o[nt][r]);
      }
    __syncthreads();
  }
}

// ---------------- Depthwise 3x3 conv + bias + tanh-GELU, 4ch/thread ----------------
#define CONV_T 8
__global__ __launch_bounds__(384)
void conv_gelu_kern(const unsigned short* __restrict__ x1, const unsigned short* __restrict__ wt,
                    const float* __restrict__ kb, unsigned short* __restrict__ out)
{
  int tid = threadIdx.x;
  int c0 = tid * 4;
  ushort4 wv[9];
  #pragma unroll
  for (int j = 0; j < 9; j++) wv[j] = *(const ushort4*)&wt[j * NHID + c0];
  float4 bias = *(const float4*)&kb[c0];

  int n0 = blockIdx.x * CONV_T;
  for (int t = 0; t < CONV_T; t++){
    int n = n0 + t;                             // wave-uniform
    int rem = n % 3136;
    int h = rem / 56, w = rem % 56;
    float a0 = 0.f, a1 = 0.f, a2 = 0.f, a3 = 0.f;
    #pragma unroll
    for (int dh = -1; dh <= 1; dh++){
      int hh = h + dh; if (hh < 0 || hh >= 56) continue;
      #pragma unroll
      for (int dw = -1; dw <= 1; dw++){
        int ww = w + dw; if (ww < 0 || ww >= 56) continue;
        ushort4 rv = *(const ushort4*)&x1[((size_t)n + dh*56 + dw) * NHID + c0];
        int j = (dh + 1) * 3 + (dw + 1);
        a0 += bf2f(rv.x) * bf2f(wv[j].x);
        a1 += bf2f(rv.y) * bf2f(wv[j].y);
        a2 += bf2f(rv.z) * bf2f(wv[j].z);
        a3 += bf2f(rv.w) * bf2f(wv[j].w);
      }
    }
    float v0 = a0 + bias.x, v1 = a1 + bias.y, v2 = a2 + bias.z, v3 = a3 + bias.w;
    // tanh-form GELU: v * sigmoid(2c*(v + 0.044715 v^3)), 2c = 1.5957691216
    float g0, g1, g2, g3;
    {
      float u, tq, z, e, s;
      u = v0*v0; tq = fmaf(u, 0.07135481627f, 1.5957691216f); z = v0*tq;
      e = __expf(-z); s = __builtin_amdgcn_rcpf(1.f + e); g0 = v0 * s;
      u = v1*v1; tq = fmaf(u, 0.07135481627f, 1.5957691216f); z = v1*tq;
      e = __expf(-z); s = __builtin_amdgcn_rcpf(1.f + e); g1 = v1 * s;
      u = v2*v2; tq = fmaf(u, 0.07135481627f, 1.5957691216f); z = v2*tq;
      e = __expf(-z); s = __builtin_amdgcn_rcpf(1.f + e); g2 = v2 * s;
      u = v3*v3; tq = fmaf(u, 0.07135481627f, 1.5957691216f); z = v3*tq;
      e = __expf(-z); s = __builtin_amdgcn_rcpf(1.f + e); g3 = v3 * s;
    }
    unsigned int pa, pb;
    asm("v_cvt_pk_bf16_f32 %0, %1, %2" : "=v"(pa) : "v"(g0), "v"(g1));
    asm("v_cvt_pk_bf16_f32 %0, %1, %2" : "=v"(pb) : "v"(g2), "v"(g3));
    uint2 w2; w2.x = pa; w2.y = pb;
    *(uint2*)&out[(size_t)n * NHID + c0] = w2;
  }
}

extern "C" void kernel_launch(void* const* d_in, const int* in_sizes, int n_in,
                              void* d_out, int out_size, void* d_ws, size_t ws_size,
                              hipStream_t stream)
{
  const float* x      = (const float*)d_in[0];
  const float* ln1_g  = (const float*)d_in[1];
  const float* ln1_b  = (const float*)d_in[2];
  const float* qkv_w  = (const float*)d_in[3];
  const float* proj_w = (const float*)d_in[4];
  const float* proj_b = (const float*)d_in[5];
  const float* ln2_g  = (const float*)d_in[6];
  const float* ln2_b  = (const float*)d_in[7];
  const float* fc1_w  = (const float*)d_in[8];
  const float* fc1_b  = (const float*)d_in[9];
  const float* dw_k   = (const float*)d_in[10];
  const float* dw_b   = (const float*)d_in[11];
  const float* fc2_w  = (const float*)d_in[12];
  const float* fc2_b  = (const float*)d_in[13];
  float* outp = (float*)d_out;

  const size_t WS_NEED = 90270720;
  if (ws_size < WS_NEED) return;
  char* ws = (char*)d_ws;
  unsigned short* xw   = (unsigned short*)(ws);               // 25088*384*2
  unsigned short* qkvh = (unsigned short*)(ws + 19267584);    // 25088*1152*2
  unsigned short* xn2q = (unsigned short*)(ws);               // 12544*384*2
  unsigned short* x1q  = (unsigned short*)(ws + 9633792);     // 12544*1536*2
  unsigned short* x1gq = (unsigned short*)(ws + 48168960);    // 12544*1536*2
  unsigned short* wqkv = (unsigned short*)(ws + 86704128);    // [1152][384]
  unsigned short* wproj= (unsigned short*)(ws + 87588864);    // [384][384]
  unsigned short* wfc1 = (unsigned short*)(ws + 87883776);    // [1536][384]
  unsigned short* wfc2 = (unsigned short*)(ws + 89063424);    // [384][1536]
  unsigned short* wdw  = (unsigned short*)(ws + 90243072);    // [9][1536]

  cvtT_kern<<<dim3(12, 36), 256, 0, stream>>>(qkv_w,  wqkv, 384, 1152);
  cvtT_kern<<<dim3(12, 12), 256, 0, stream>>>(proj_w, wproj, 384, 384);
  cvtT_kern<<<dim3(12, 48), 256, 0, stream>>>(fc1_w,  wfc1, 384, 1536);
  cvtT_kern<<<dim3(48, 12), 256, 0, stream>>>(fc2_w,  wfc2, 1536, 384);
  cvtDW_kern<<<(NHID*9 + 255)/256, 256, 0, stream>>>(dw_k, wdw);

  // ---- attention path, two batch halves (25088 tokens = 512 windows each) ----
  for (int hf = 0; hf < 2; hf++){
    int ro = hf * 25088;
    ln_kern<<<25088, 64, 0, stream>>>(x, ln1_g, ln1_b, xw, ro, 1);
    gemm_kern<0,128><<<dim3(196, 9), 256, 0, stream>>>(xw, 384, wqkv, 384, 1152,
                                                       nullptr, nullptr, qkvh, 0);
    attn_kern<<<6144, 64, 0, stream>>>(qkvh);
    gemm_kern<2,64><<<dim3(196, 6), 256, 0, stream>>>(qkvh, 1152, wproj, 384, 384,
                                                      proj_b, x, outp, ro);
  }

  // ---- MLP path, four batch quarters (12544 tokens = 4 whole images each) ----
  for (int qt = 0; qt < 4; qt++){
    int ro = qt * 12544;
    ln_kern<<<12544, 64, 0, stream>>>(outp + (size_t)ro * CDIM, ln2_g, ln2_b, xn2q, 0, 0);
    gemm_kern<1,128><<<dim3(98, 12), 256, 0, stream>>>(xn2q, 384, wfc1, 384, 1536,
                                                       fc1_b, nullptr, x1q, 0);
    conv_gelu_kern<<<12544 / CONV_T, 384, 0, stream>>>(x1q, wdw, dw_b, x1gq);
    gemm_kern<3,64><<<dim3(98, 6), 256, 0, stream>>>(x1gq, 1536, wfc2, 1536, 384,
                                                     fc2_b, outp, outp, ro);
  }
}

// Round 8
// 672.073 us; speedup vs baseline: 3.7306x; 1.1686x over previous
//
#include <hip/hip_runtime.h>

// Swin block. fp32 I/O, bf16 internal MFMA operands, fp32 trunk.
// R7: conv_gelu — register sliding window (3 loads/token) + f16 x1 path with
//     packed v_pk_fma_f16 (fc1 now writes f16; dw weights f16).

using bf16x8 = __attribute__((ext_vector_type(8))) short;
using f32x4  = __attribute__((ext_vector_type(4))) float;
using h16x4  = __attribute__((ext_vector_type(4))) _Float16;

#define CDIM  384
#define N3C   1152
#define NHID  1536

__device__ __forceinline__ float bf2f(unsigned short u){
  union { unsigned int i; float f; } x; x.i = ((unsigned int)u) << 16; return x.f;
}
__device__ __forceinline__ unsigned short f2bf(float f){
  union { float f; unsigned int i; } x; x.f = f;
  unsigned int r = x.i + 0x7fffu + ((x.i >> 16) & 1u);   // RNE
  return (unsigned short)(r >> 16);
}
__device__ __forceinline__ void gload16(const void* g, void* l){
  __builtin_amdgcn_global_load_lds(
      (const __attribute__((address_space(1))) unsigned int*)g,
      (__attribute__((address_space(3))) unsigned int*)l, 16, 0, 0);
}

// ---------------- transpose-convert: wt[n*K+k] = bf16(w[k*N+n]) ----------------
__global__ __launch_bounds__(256)
void cvtT_kern(const float* __restrict__ w, unsigned short* __restrict__ wt, int K, int N){
  __shared__ unsigned short t[32][33];
  int bk = blockIdx.x, bn = blockIdx.y;
  int tr = threadIdx.x >> 5, tc = threadIdx.x & 31;
  #pragma unroll
  for (int r = tr; r < 32; r += 8)
    t[r][tc] = f2bf(w[(size_t)(bk*32 + r) * N + bn*32 + tc]);
  __syncthreads();
  #pragma unroll
  for (int r = tr; r < 32; r += 8)
    wt[(size_t)(bn*32 + r) * K + bk*32 + tc] = t[tc][r];
}

// ---------------- dw weights: [1536][9] fp32 -> [9][1536] f16 ----------------
__global__ __launch_bounds__(256)
void cvtDW_kern(const float* __restrict__ k, unsigned short* __restrict__ wt){
  int i = blockIdx.x * 256 + threadIdx.x;
  if (i < NHID * 9){
    int c = i / 9, tap = i % 9;
    _Float16 hv = (_Float16)k[i];
    union { _Float16 h; unsigned short u; } cvt; cvt.h = hv;
    wt[tap * NHID + c] = cvt.u;
  }
}

// ---------------- LayerNorm (+optional roll+window-partition gather), fp32 in, bf16 out ----------
__global__ __launch_bounds__(64)
void ln_kern(const float* __restrict__ xin, const float* __restrict__ g,
             const float* __restrict__ bsh, unsigned short* __restrict__ out,
             int row_off, int do_shift)
{
  int blk = blockIdx.x, t = threadIdx.x;
  size_t src;
  if (do_shift){
    int gl = row_off + blk;
    int bb = gl / 3136, rem = gl % 3136;
    int wi = rem / 49, l = rem % 49;
    int h = (wi >> 3) * 7 + l / 7;
    int w = (wi & 7) * 7 + l % 7;
    int sh = h + 3; if (sh >= 56) sh -= 56;    // roll(-3)
    int sw = w + 3; if (sw >= 56) sw -= 56;
    src = ((size_t)bb * 3136 + sh * 56 + sw) * CDIM;
  } else {
    src = (size_t)blk * CDIM;
  }
  float v[6]; float s = 0.f;
  #pragma unroll
  for (int j = 0; j < 6; j++){ v[j] = xin[src + j*64 + t]; s += v[j]; }
  #pragma unroll
  for (int m = 32; m >= 1; m >>= 1) s += __shfl_xor(s, m);
  float mean = s * (1.f/384.f);
  float q = 0.f;
  #pragma unroll
  for (int j = 0; j < 6; j++){ float d = v[j] - mean; q += d * d; }
  #pragma unroll
  for (int m = 32; m >= 1; m >>= 1) q += __shfl_xor(q, m);
  float rstd = rsqrtf(q * (1.f/384.f) + 1e-5f);
  size_t dst = (size_t)blk * CDIM;
  #pragma unroll
  for (int j = 0; j < 6; j++){
    int c = j*64 + t;
    out[dst + c] = f2bf((v[j] - mean) * rstd * g[c] + bsh[c]);
  }
}

// ---------------- MFMA GEMM, m97-style: C[M,N] = A[M,K] @ Bt[N,K]^T ----------------
// MODE 0: bf16 out. 1: +bias, f16 out (feeds conv). 2: proj epilogue. 3: fc2 epilogue.
template<int MODE, int BN>
__global__ __launch_bounds__(256)
void gemm_kern(const unsigned short* __restrict__ A, int lda,
               const unsigned short* __restrict__ Bt, int K, int N,
               const float* __restrict__ bias, const float* __restrict__ resid,
               void* __restrict__ outv, int row_off)
{
  constexpr int NI = BN / 32;
  __shared__ __align__(16) unsigned short Al[128 * 32];
  __shared__ __align__(16) unsigned short Bl[BN * 32];
  int tid = threadIdx.x;
  int lane = tid & 63, wv = tid >> 6;
  int m0 = blockIdx.x * 128, n0 = blockIdx.y * BN;
  const int wrow = (wv >> 1) * 64;
  const int wcol = (wv & 1) * (BN / 2);
  const int lr = lane & 15, lk = (lane >> 4) * 8;
  f32x4 acc[4][NI] = {};
  for (int k0 = 0; k0 < K; k0 += 32){
    __syncthreads();
    #pragma unroll
    for (int i = 0; i < 2; i++){
      int c = i*256 + tid;
      gload16(&A[(size_t)(m0 + (c >> 2)) * lda + k0 + (c & 3) * 8],
              &Al[(i*256 + wv*64) * 8]);
    }
    #pragma unroll
    for (int i = 0; i < BN/64; i++){
      int c = i*256 + tid;
      gload16(&Bt[(size_t)(n0 + (c >> 2)) * K + k0 + (c & 3) * 8],
              &Bl[(i*256 + wv*64) * 8]);
    }
    __syncthreads();
    bf16x8 af[4], bfr[NI];
    #pragma unroll
    for (int mi = 0; mi < 4; mi++) af[mi] = *(const bf16x8*)&Al[(wrow + mi*16 + lr)*32 + lk];
    #pragma unroll
    for (int ni = 0; ni < NI; ni++) bfr[ni] = *(const bf16x8*)&Bl[(wcol + ni*16 + lr)*32 + lk];
    #pragma unroll
    for (int mi = 0; mi < 4; mi++)
      #pragma unroll
      for (int ni = 0; ni < NI; ni++)
        acc[mi][ni] = __builtin_amdgcn_mfma_f32_16x16x32_bf16(af[mi], bfr[ni], acc[mi][ni], 0, 0, 0);
  }
  #pragma unroll
  for (int mi = 0; mi < 4; mi++)
  #pragma unroll
  for (int ni = 0; ni < NI; ni++)
  #pragma unroll
  for (int j = 0; j < 4; j++){
    int row = m0 + wrow + mi*16 + (lane >> 4) * 4 + j;   // C/D layout (m89/m91)
    int col = n0 + wcol + ni*16 + lr;
    float val = acc[mi][ni][j];
    if (MODE == 0){
      ((unsigned short*)outv)[(size_t)row * N + col] = f2bf(val);
    } else if (MODE == 1){
      union { _Float16 h; unsigned short u; } cvt;
      cvt.h = (_Float16)(val + bias[col]);
      ((unsigned short*)outv)[(size_t)row * N + col] = cvt.u;
    } else if (MODE == 2){
      val += bias[col];
      int gl = row_off + row;
      int bb = gl / 3136, rem = gl % 3136;
      int wi = rem / 49, l = rem % 49;
      int n = ((wi >> 3) * 7 + l / 7) * 56 + (wi & 7) * 7 + l % 7;  // window reverse
      size_t idx = ((size_t)bb * 3136 + n) * CDIM + col;
      ((float*)outv)[idx] = resid[idx] + val;
    } else {
      size_t idx = (size_t)(row_off + row) * CDIM + col;
      ((float*)outv)[idx] = resid[idx] + val + bias[col];
    }
  }
}

// ---------------- Windowed attention, MFMA version: one wave per (window, head) -------------
__global__ __launch_bounds__(64)
void attn_kern(unsigned short* __restrict__ qkv)
{
  __shared__ __align__(16) unsigned short Vt[32 * 64];   // [d][key], XOR-swizzled rows
  __shared__ __align__(16) unsigned short Pl[16 * 64];   // [q][key], XOR-swizzled rows
  __shared__ unsigned char idt[49];
  int blk = blockIdx.x;
  int win = blk / 12, head = blk % 12;
  int l = threadIdx.x;
  int g = l >> 4, q15 = l & 15;
  size_t base = (size_t)win * 49 * N3C + (size_t)head * 32;
  const unsigned short* kp = qkv + base + 384;
  const unsigned short* vp = qkv + base + 768;

  int wi = win & 63;
  if (l < 49){
    int h = (wi >> 3) * 7 + l / 7;
    int w = (wi & 7) * 7 + l % 7;
    idt[l] = (unsigned char)((h < 49 ? 0 : (h < 53 ? 1 : 2)) * 3 +
                             (w < 49 ? 0 : (w < 53 ? 1 : 2)));
  }
  #pragma unroll
  for (int it = 0; it < 4; it++){
    int c = it * 64 + l;
    int key = c >> 2, keyc = min(key, 48), d0 = (c & 3) * 8;
    bf16x8 v = *(const bf16x8*)&vp[(size_t)keyc * N3C + d0];
    #pragma unroll
    for (int j = 0; j < 8; j++){
      int d = d0 + j;
      *(unsigned short*)((char*)Vt + d * 128 + ((key * 2) ^ ((d & 7) << 4))) =
          (unsigned short)v[j];
    }
  }
  __syncthreads();

  bf16x8 kf[4];
  #pragma unroll
  for (int kt = 0; kt < 4; kt++){
    int krow = min(kt * 16 + q15, 48);
    kf[kt] = *(const bf16x8*)&kp[(size_t)krow * N3C + g * 8];
  }
  bf16x8 vf[2][2];
  #pragma unroll
  for (int kb = 0; kb < 2; kb++)
    #pragma unroll
    for (int nt = 0; nt < 2; nt++){
      int n = nt * 16 + q15;
      vf[kb][nt] = *(const bf16x8*)((char*)Vt + n * 128 + ((kb * 64 + g * 16) ^ ((n & 7) << 4)));
    }
  unsigned int kidp[4];
  #pragma unroll
  for (int kt = 0; kt < 4; kt++){
    unsigned int p = 0;
    #pragma unroll
    for (int r = 0; r < 4; r++)
      p |= ((unsigned int)idt[min(kt * 16 + 4 * g + r, 48)]) << (8 * r);
    kidp[kt] = p;
  }

  const float scale = 0.17677669529663687f;
  const f32x4 zf = {0.f, 0.f, 0.f, 0.f};
  #pragma unroll
  for (int qt = 0; qt < 4; qt++){
    int qrow = min(qt * 16 + q15, 48);
    bf16x8 qf = *(const bf16x8*)&qkv[base + (size_t)qrow * N3C + g * 8];
    f32x4 s[4];
    #pragma unroll
    for (int kt = 0; kt < 4; kt++)
      s[kt] = __builtin_amdgcn_mfma_f32_16x16x32_bf16(kf[kt], qf, zf, 0, 0, 0);
    int qid = idt[qrow];
    float mx = -1e30f;
    #pragma unroll
    for (int kt = 0; kt < 4; kt++)
      #pragma unroll
      for (int r = 0; r < 4; r++){
        float x = s[kt][r] * scale;
        int idk = (kidp[kt] >> (8 * r)) & 255;
        x += (idk != qid) ? -100.f : 0.f;
        if (kt * 16 + 4 * g + r >= 49) x = -3.0e38f;   // padded key -> exp 0
        s[kt][r] = x;
        mx = fmaxf(mx, x);
      }
    mx = fmaxf(mx, __shfl_xor(mx, 16));
    mx = fmaxf(mx, __shfl_xor(mx, 32));
    float sum = 0.f;
    #pragma unroll
    for (int kt = 0; kt < 4; kt++)
      #pragma unroll
      for (int r = 0; r < 4; r++){
        float e = expf(s[kt][r] - mx);
        s[kt][r] = e; sum += e;
      }
    sum += __shfl_xor(sum, 16);
    sum += __shfl_xor(sum, 32);
    float inv = 1.f / sum;
    #pragma unroll
    for (int kt = 0; kt < 4; kt++){
      float e0 = s[kt][0] * inv, e1 = s[kt][1] * inv;
      float e2 = s[kt][2] * inv, e3 = s[kt][3] * inv;
      unsigned int pa, pb;
      asm("v_cvt_pk_bf16_f32 %0, %1, %2" : "=v"(pa) : "v"(e0), "v"(e1));
      asm("v_cvt_pk_bf16_f32 %0, %1, %2" : "=v"(pb) : "v"(e2), "v"(e3));
      uint2 w2; w2.x = pa; w2.y = pb;
      *(uint2*)((char*)Pl + q15 * 128 + ((kt * 32 + g * 8) ^ ((q15 & 7) << 4))) = w2;
    }
    __syncthreads();
    f32x4 o[2] = {zf, zf};
    #pragma unroll
    for (int kb = 0; kb < 2; kb++){
      bf16x8 pf = *(const bf16x8*)((char*)Pl + q15 * 128 + ((kb * 64 + g * 16) ^ ((q15 & 7) << 4)));
      #pragma unroll
      for (int nt = 0; nt < 2; nt++)
        o[nt] = __builtin_amdgcn_mfma_f32_16x16x32_bf16(pf, vf[kb][nt], o[nt], 0, 0, 0);
    }
    #pragma unroll
    for (int nt = 0; nt < 2; nt++)
      #pragma unroll
      for (int r = 0; r < 4; r++){
        int qp = qt * 16 + 4 * g + r;
        if (qp < 49)
          qkv[base + (size_t)qp * N3C + nt * 16 + q15] = f2bf(o[nt][r]);
      }
    __syncthreads();
  }
}

// ---------------- Depthwise 3x3 conv + bias + tanh-GELU ----------------
// R7: f16 input, packed v_pk_fma_f16, register sliding window (3 loads/token).
#define CONV_T 8
__global__ __launch_bounds__(384)
void conv_gelu_kern(const unsigned short* __restrict__ x1, const unsigned short* __restrict__ wt,
                    const float* __restrict__ kb, unsigned short* __restrict__ out)
{
  int tid = threadIdx.x;
  int c0 = tid * 4;
  h16x4 wv[9];
  #pragma unroll
  for (int j = 0; j < 9; j++) wv[j] = *(const h16x4*)&wt[j * NHID + c0];
  float4 bias = *(const float4*)&kb[c0];

  int n0 = blockIdx.x * CONV_T;            // strip start; 56%8==0 so never crosses a row
  int rem = n0 % 3136;
  int h = rem / 56, w0 = rem % 56;
  const int hm = (h > 0), hp = (h < 55);
  const unsigned short* base = x1 + (size_t)n0 * NHID + c0;   // (h, w0)
  const h16x4 z4 = {(_Float16)0, (_Float16)0, (_Float16)0, (_Float16)0};

  h16x4 win[3][3];   // [row: 0=h-1,1=h,2=h+1][slot]
  // prologue: col w0-1 -> slot 0, col w0 -> slot 1
  if (w0 > 0){
    win[0][0] = hm ? *(const h16x4*)(base + (-56 - 1) * NHID) : z4;
    win[1][0] =      *(const h16x4*)(base - NHID);
    win[2][0] = hp ? *(const h16x4*)(base + (56 - 1) * NHID) : z4;
  } else { win[0][0] = z4; win[1][0] = z4; win[2][0] = z4; }
  win[0][1] = hm ? *(const h16x4*)(base - 56 * NHID) : z4;
  win[1][1] =      *(const h16x4*)(base);
  win[2][1] = hp ? *(const h16x4*)(base + 56 * NHID) : z4;

  #pragma unroll
  for (int t = 0; t < CONV_T; t++){
    int w = w0 + t;
    const int snew = (t + 2) % 3;
    if (w + 1 <= 55){
      const unsigned short* p = base + (t + 1) * NHID;
      win[0][snew] = hm ? *(const h16x4*)(p - 56 * NHID) : z4;
      win[1][snew] =      *(const h16x4*)(p);
      win[2][snew] = hp ? *(const h16x4*)(p + 56 * NHID) : z4;
    } else { win[0][snew] = z4; win[1][snew] = z4; win[2][snew] = z4; }
    const int s0 = t % 3, s1 = (t + 1) % 3, s2 = snew;
    h16x4 acc = win[0][s0] * wv[0];
    acc += win[0][s1] * wv[1];
    acc += win[0][s2] * wv[2];
    acc += win[1][s0] * wv[3];
    acc += win[1][s1] * wv[4];
    acc += win[1][s2] * wv[5];
    acc += win[2][s0] * wv[6];
    acc += win[2][s1] * wv[7];
    acc += win[2][s2] * wv[8];
    float v0 = (float)acc[0] + bias.x;
    float v1 = (float)acc[1] + bias.y;
    float v2 = (float)acc[2] + bias.z;
    float v3 = (float)acc[3] + bias.w;
    // tanh-form GELU: v * sigmoid(2c*(v + 0.044715 v^3)), 2c = 1.5957691216
    float g0, g1, g2, g3;
    {
      float u, tq, z, e, s;
      u = v0*v0; tq = fmaf(u, 0.07135481627f, 1.5957691216f); z = v0*tq;
      e = __expf(-z); s = __builtin_amdgcn_rcpf(1.f + e); g0 = v0 * s;
      u = v1*v1; tq = fmaf(u, 0.07135481627f, 1.5957691216f); z = v1*tq;
      e = __expf(-z); s = __builtin_amdgcn_rcpf(1.f + e); g1 = v1 * s;
      u = v2*v2; tq = fmaf(u, 0.07135481627f, 1.5957691216f); z = v2*tq;
      e = __expf(-z); s = __builtin_amdgcn_rcpf(1.f + e); g2 = v2 * s;
      u = v3*v3; tq = fmaf(u, 0.07135481627f, 1.5957691216f); z = v3*tq;
      e = __expf(-z); s = __builtin_amdgcn_rcpf(1.f + e); g3 = v3 * s;
    }
    unsigned int pa, pb;
    asm("v_cvt_pk_bf16_f32 %0, %1, %2" : "=v"(pa) : "v"(g0), "v"(g1));
    asm("v_cvt_pk_bf16_f32 %0, %1, %2" : "=v"(pb) : "v"(g2), "v"(g3));
    uint2 w2; w2.x = pa; w2.y = pb;
    *(uint2*)&out[(size_t)(n0 + t) * NHID + c0] = w2;
  }
}

extern "C" void kernel_launch(void* const* d_in, const int* in_sizes, int n_in,
                              void* d_out, int out_size, void* d_ws, size_t ws_size,
                              hipStream_t stream)
{
  const float* x      = (const float*)d_in[0];
  const float* ln1_g  = (const float*)d_in[1];
  const float* ln1_b  = (const float*)d_in[2];
  const float* qkv_w  = (const float*)d_in[3];
  const float* proj_w = (const float*)d_in[4];
  const float* proj_b = (const float*)d_in[5];
  const float* ln2_g  = (const float*)d_in[6];
  const float* ln2_b  = (const float*)d_in[7];
  const float* fc1_w  = (const float*)d_in[8];
  const float* fc1_b  = (const float*)d_in[9];
  const float* dw_k   = (const float*)d_in[10];
  const float* dw_b   = (const float*)d_in[11];
  const float* fc2_w  = (const float*)d_in[12];
  const float* fc2_b  = (const float*)d_in[13];
  float* outp = (float*)d_out;

  const size_t WS_NEED = 90270720;
  if (ws_size < WS_NEED) return;
  char* ws = (char*)d_ws;
  unsigned short* xw   = (unsigned short*)(ws);               // 25088*384*2
  unsigned short* qkvh = (unsigned short*)(ws + 19267584);    // 25088*1152*2
  unsigned short* xn2q = (unsigned short*)(ws);               // 12544*384*2
  unsigned short* x1q  = (unsigned short*)(ws + 9633792);     // 12544*1536*2 (f16)
  unsigned short* x1gq = (unsigned short*)(ws + 48168960);    // 12544*1536*2 (bf16)
  unsigned short* wqkv = (unsigned short*)(ws + 86704128);    // [1152][384]
  unsigned short* wproj= (unsigned short*)(ws + 87588864);    // [384][384]
  unsigned short* wfc1 = (unsigned short*)(ws + 87883776);    // [1536][384]
  unsigned short* wfc2 = (unsigned short*)(ws + 89063424);    // [384][1536]
  unsigned short* wdw  = (unsigned short*)(ws + 90243072);    // [9][1536] (f16)

  cvtT_kern<<<dim3(12, 36), 256, 0, stream>>>(qkv_w,  wqkv, 384, 1152);
  cvtT_kern<<<dim3(12, 12), 256, 0, stream>>>(proj_w, wproj, 384, 384);
  cvtT_kern<<<dim3(12, 48), 256, 0, stream>>>(fc1_w,  wfc1, 384, 1536);
  cvtT_kern<<<dim3(48, 12), 256, 0, stream>>>(fc2_w,  wfc2, 1536, 384);
  cvtDW_kern<<<(NHID*9 + 255)/256, 256, 0, stream>>>(dw_k, wdw);

  // ---- attention path, two batch halves (25088 tokens = 512 windows each) ----
  for (int hf = 0; hf < 2; hf++){
    int ro = hf * 25088;
    ln_kern<<<25088, 64, 0, stream>>>(x, ln1_g, ln1_b, xw, ro, 1);
    gemm_kern<0,128><<<dim3(196, 9), 256, 0, stream>>>(xw, 384, wqkv, 384, 1152,
                                                       nullptr, nullptr, qkvh, 0);
    attn_kern<<<6144, 64, 0, stream>>>(qkvh);
    gemm_kern<2,64><<<dim3(196, 6), 256, 0, stream>>>(qkvh, 1152, wproj, 384, 384,
                                                      proj_b, x, outp, ro);
  }

  // ---- MLP path, four batch quarters (12544 tokens = 4 whole images each) ----
  for (int qt = 0; qt < 4; qt++){
    int ro = qt * 12544;
    ln_kern<<<12544, 64, 0, stream>>>(outp + (size_t)ro * CDIM, ln2_g, ln2_b, xn2q, 0, 0);
    gemm_kern<1,128><<<dim3(98, 12), 256, 0, stream>>>(xn2q, 384, wfc1, 384, 1536,
                                                       fc1_b, nullptr, x1q, 0);
    conv_gelu_kern<<<12544 / CONV_T, 384, 0, stream>>>(x1q, wdw, dw_b, x1gq);
    gemm_kern<3,64><<<dim3(98, 6), 256, 0, stream>>>(x1gq, 1536, wfc2, 1536, 384,
                                                     fc2_b, outp, outp, ro);
  }
}